// Round 2
// baseline (500.665 us; speedup 1.0000x reference)
//
#include <hip/hip_runtime.h>
#include <hip/hip_bf16.h>

using bf16 = __hip_bfloat16;

typedef __attribute__((ext_vector_type(8))) short short8;   // 8 x bf16 (4 VGPRs)
typedef __attribute__((ext_vector_type(4))) float f32x4;    // MFMA C/D

// MaskedMSA: B=4, S=2048, E=1024, HIDDEN=1024, HEADS=16
// Reference reshape mixes seq/hidden: with t=16u+r (u<128, r<16):
//   q[b,h,t,e] = qkv[b, 128h+u, 192r +   0 + e]
//   k[b,h,t,e] = qkv[b, 128h+u, 192r +  64 + e]
//   v[b,h,t,e] = qkv[b, 128h+u, 192r + 128 + e]
// Output: sa[b,h,t,e] -> out row 128h+u, col 64r+e. Causal mask on permuted t.
// Q columns of W_qkv/b_qkv are pre-scaled by scale*log2(e): exp2-domain scores.
// Attention computes S^T = mfma(K,Q) and O^T = mfma(Vt,P): softmax is
// lane-local (lane = q row), P transform is 4x ds_write_b64 + 2x ds_read_b128.
//
// R1 lesson: pipelining the kt-loop (1 barrier/iter, K/V prefetch) was neutral
// (165->172us) -> bottleneck is latency with too few resident waves, not
// barrier structure. R2: un-pair q-tiles (grid 64x32, one qt per block),
// launch_bounds(256,8) -> 8 blocks/CU (was grid-capped at 4).

#define CEXP 0.03188127742677263f  // (2*1024)^-0.5 * log2(e)

__device__ __forceinline__ unsigned short f2bf(float v) {
  bf16 h = __float2bfloat16(v);
  return *(unsigned short*)&h;
}
__device__ __forceinline__ unsigned int pack2bf(float a, float b) {
  return (unsigned int)f2bf(a) | ((unsigned int)f2bf(b) << 16);
}

// async global->LDS, 16B per lane; LDS dest = wave-uniform base + lane*16.
__device__ __forceinline__ void gload_lds16(const void* g, void* lds) {
  __builtin_amdgcn_global_load_lds(
      (const __attribute__((address_space(1))) unsigned int*)(g),
      (__attribute__((address_space(3))) unsigned int*)(lds), 16, 0, 0);
}

// ---- dtype detect: flag=1 if fp32 I/O, flag=0 if bf16 I/O.
__global__ void detect_kernel(const unsigned int* __restrict__ x, int* __restrict__ flag) {
  unsigned int w = x[threadIdx.x];
  unsigned int e = (w >> 7) & 0xFF;
  bool inband = (e >= 96 && e <= 133);
  unsigned long long m = __ballot(inband);
  if (threadIdx.x == 0) flag[0] = (__popcll(m) >= 48) ? 0 : 1;
}

// ---- convert n8*8 elements to bf16 (copy if already bf16)
__global__ __launch_bounds__(256) void convert_kernel(
    const void* __restrict__ src, bf16* __restrict__ dst, int n8,
    const int* __restrict__ flag) {
  int i = blockIdx.x * 256 + threadIdx.x;
  if (i >= n8) return;
  uint4 outv;
  if (*flag) {
    const float4* s = (const float4*)src + (size_t)i * 2;
    float4 a = s[0], b = s[1];
    outv.x = pack2bf(a.x, a.y);
    outv.y = pack2bf(a.z, a.w);
    outv.z = pack2bf(b.x, b.y);
    outv.w = pack2bf(b.z, b.w);
  } else {
    outv = ((const uint4*)src)[i];
  }
  ((uint4*)dst)[i] = outv;
}

// ---- b_qkv convert with Q-column pre-scale (cols with (i%192)<64)
__global__ void convert_bias_qkv(const void* __restrict__ src, bf16* __restrict__ dst,
                                 const int* __restrict__ flag) {
  int i = blockIdx.x * 256 + threadIdx.x;
  if (i >= 3072) return;
  float v = (*flag) ? ((const float*)src)[i]
                    : __bfloat162float(((const bf16*)src)[i]);
  if ((i % 192) < 64) v *= CEXP;
  dst[i] = __float2bfloat16(v);
}

// ---- transpose src[R][C] -> dst[C][R] (bf16 out); qscale: scale rows n with
// (n%192)<64 by CEXP (W_qkv Q columns -> exp2 domain).
__global__ __launch_bounds__(256) void transpose_bf16(
    const void* __restrict__ src, bf16* __restrict__ dst, int R, int Cc,
    const int* __restrict__ flag, int qscale) {
  __shared__ float tile[32][33];
  const int c0 = blockIdx.x * 32, r0 = blockIdx.y * 32;
  const int tx = threadIdx.x & 31, ty = threadIdx.x >> 5;  // 32 x 8
  const bool f32 = (*flag != 0);
#pragma unroll
  for (int it = 0; it < 4; ++it) {
    int r = ty + it * 8;
    float v;
    if (f32) v = ((const float*)src)[(size_t)(r0 + r) * Cc + c0 + tx];
    else     v = __bfloat162float(((const bf16*)src)[(size_t)(r0 + r) * Cc + c0 + tx]);
    tile[r][tx] = v;
  }
  __syncthreads();
#pragma unroll
  for (int it = 0; it < 4; ++it) {
    int r = ty + it * 8;   // dst row n = c0 + r
    float vv = tile[tx][r];
    if (qscale && (((c0 + r) % 192) < 64)) vv *= CEXP;
    dst[(size_t)(c0 + r) * R + r0 + tx] = __float2bfloat16(vv);
  }
}

// ---------------- MFMA GEMM (m97 pattern): C[M,N] = A[M,K] @ BT[N,K]^T + bias
__global__ __launch_bounds__(256) void gemm_mfma(
    const bf16* __restrict__ A, const bf16* __restrict__ BT,
    const bf16* __restrict__ bias, void* __restrict__ C,
    int M, int N, int K, int store_mode, const int* __restrict__ flag)
{
  __shared__ alignas(16) unsigned short As[128 * 32];  // [m][k] contiguous
  __shared__ alignas(16) unsigned short Bs[128 * 32];  // [n][k] contiguous
  const bool store_f32 = store_mode && (*flag != 0);
  const int tid = threadIdx.x;
  const int wave = tid >> 6, lane = tid & 63;
  const int l15 = lane & 15, l4 = lane >> 4;
  const int m0 = blockIdx.y * 128, n0 = blockIdx.x * 128;
  const int wm = (wave & 1) * 64, wn = (wave >> 1) * 64;

  const int srow = wave * 32 + (lane >> 2);
  const int skv = (lane & 3) * 8;
  const bf16* ga = A + (size_t)(m0 + srow) * K + skv;
  const bf16* gb = BT + (size_t)(n0 + srow) * K + skv;
  unsigned short* la = As + (wave * 32) * 32;
  unsigned short* lb = Bs + (wave * 32) * 32;

  f32x4 acc[4][4] = {};

  for (int k0 = 0; k0 < K; k0 += 32) {
    __syncthreads();
    gload_lds16(ga, la);
    gload_lds16(ga + (size_t)16 * K, la + 16 * 32);
    gload_lds16(gb, lb);
    gload_lds16(gb + (size_t)16 * K, lb + 16 * 32);
    ga += 32; gb += 32;
    __syncthreads();

    short8 af[4], bfr[4];
#pragma unroll
    for (int i = 0; i < 4; ++i) {
      af[i]  = *(const short8*)(As + (wm + i * 16 + l15) * 32 + l4 * 8);
      bfr[i] = *(const short8*)(Bs + (wn + i * 16 + l15) * 32 + l4 * 8);
    }
#pragma unroll
    for (int i = 0; i < 4; ++i)
#pragma unroll
      for (int j = 0; j < 4; ++j)
        acc[i][j] = __builtin_amdgcn_mfma_f32_16x16x32_bf16(af[i], bfr[j], acc[i][j], 0, 0, 0);
  }

#pragma unroll
  for (int j = 0; j < 4; ++j) {
    const int n = n0 + wn + j * 16 + l15;
    const float bv = __bfloat162float(bias[n]);
#pragma unroll
    for (int i = 0; i < 4; ++i) {
#pragma unroll
      for (int r = 0; r < 4; ++r) {
        const int mrow = m0 + wm + i * 16 + l4 * 4 + r;
        const float v = acc[i][j][r] + bv;
        if (store_f32) ((float*)C)[(size_t)mrow * N + n] = v;
        else           ((bf16*)C)[(size_t)mrow * N + n] = __float2bfloat16(v);
      }
    }
  }
}

// ---------------- MFMA flash attention, transposed (S^T / O^T) formulation.
// grid (64 bh, 32 y); each block owns q-tile qt = 31-y (long blocks first).
// Per wave: 16 q rows (q = l15); S^T = mfma(K, Q) -> lane-local softmax;
// P -> LDS via 4x ds_write_b64 + 2x ds_read_b128; O^T = mfma(Vt, P).
// V staged [d][key] in LDS (single buffer, 2 barriers/iter -- R0 structure).
// launch_bounds(256,8): 8 blocks/CU (LDS 18432*8=147K, VGPR<=64).
__global__ __launch_bounds__(256, 8) void attn_mfma(const bf16* __restrict__ qkv,
                                                    bf16* __restrict__ sa)
{
  __shared__ alignas(16) short Vt[64 * 72];       // [d][key], stride 72 (144B, 16B-mult)
  __shared__ alignas(16) short Ps[4][16 * 72];    // per-wave [q][key], stride 72
  const int tid = threadIdx.x;
  const int bh = blockIdx.x;
  const int qt = 31 - blockIdx.y;                 // longest blocks dispatch first
  const size_t base = (size_t)bh * 393216;        // (bh*128) * 3072
  const int wave = tid >> 6;
  const int lane = tid & 63;
  const int l15 = lane & 15;
  const int l4 = lane >> 4;
  const unsigned short* qk = (const unsigned short*)qkv;

  // V staging ownership: this thread owns key=tid&63, d-vectors dv0 and dv0+4
  const int key = tid & 63;
  const int dv0 = tid >> 6;
  const unsigned short* vbase =
      qk + base + (size_t)(key >> 4) * 3072 + (key & 15) * 192 + 128;
  short* psw = &Ps[wave][0];

  // Q B-frag: B[n=q(l15)][k=d(l4*8+j)]
  const unsigned short* pq = qk + base + (size_t)(qt * 4 + wave) * 3072 + l15 * 192 + l4 * 8;
  short8 qf0 = *(const short8*)pq;
  short8 qf1 = *(const short8*)(pq + 32);
  // V regs for kt=0
  short8 vn0 = *(const short8*)(vbase + dv0 * 8);
  short8 vn1 = *(const short8*)(vbase + (dv0 + 4) * 8);

  f32x4 o[4] = {};                 // O^T: col=q(l15), row=d(16jn+4l4+r)
  float mloc = -__builtin_inff();  // per-lane = per-q-row
  float lsum = 0.f;

  for (int kt = 0; kt <= qt; ++kt) {
    // K A-frags for this kt: A[m=key(l15)][k=d] -- issue early; the barrier
    // drain absorbs their latency alongside the V prefetch.
    short8 kf0[4], kf1[4];
#pragma unroll
    for (int t = 0; t < 4; ++t) {
      const unsigned short* pk =
          qk + base + (size_t)(kt * 4 + t) * 3072 + l15 * 192 + 64 + l4 * 8;
      kf0[t] = *(const short8*)pk;
      kf1[t] = *(const short8*)(pk + 32);
    }
    // prefetch next V tile
    short8 vx0 = vn0, vx1 = vn1;
    if (kt < qt) {
      const unsigned short* pv = vbase + (size_t)(kt + 1) * 12288;  // 4*3072
      vn0 = *(const short8*)(pv + dv0 * 8);
      vn1 = *(const short8*)(pv + (dv0 + 4) * 8);
    }
    __syncthreads();               // prior PV reads of Vt done (drains loads)
#pragma unroll
    for (int jj = 0; jj < 8; ++jj) {
      Vt[(dv0 * 8 + jj) * 72 + key] = vx0[jj];
      Vt[((dv0 + 4) * 8 + jj) * 72 + key] = vx1[jj];
    }
    __syncthreads();               // Vt ready (clean barrier: no pending vmem)

    // ---- S^T = K . Q^T : col=q(l15), row=key_local(16t+4l4+r)
    f32x4 sc[4];
#pragma unroll
    for (int t = 0; t < 4; ++t) {
      f32x4 c = {};
      c = __builtin_amdgcn_mfma_f32_16x16x32_bf16(kf0[t], qf0, c, 0, 0, 0);
      c = __builtin_amdgcn_mfma_f32_16x16x32_bf16(kf1[t], qf1, c, 0, 0, 0);
      sc[t] = c;
    }

    if (kt == qt) {                // wave-uniform diag branch
      const int qloc = wave * 16 + l15;
#pragma unroll
      for (int t = 0; t < 4; ++t)
#pragma unroll
        for (int r = 0; r < 4; ++r)
          if (16 * t + 4 * l4 + r > qloc) sc[t][r] = -__builtin_inff();
    }

    // ---- lane-local online softmax over this lane's 16 keys + cross-l4 reduce
    float mx = -__builtin_inff();
#pragma unroll
    for (int t = 0; t < 4; ++t)
#pragma unroll
      for (int r = 0; r < 4; ++r) mx = fmaxf(mx, sc[t][r]);
    mx = fmaxf(mx, __shfl_xor(mx, 16, 64));
    mx = fmaxf(mx, __shfl_xor(mx, 32, 64));
    const float m_new = fmaxf(mloc, mx);
    const float alpha = __builtin_amdgcn_exp2f(mloc - m_new);
    mloc = m_new;
    float s = 0.f;
    unsigned int pk2[4][2];
#pragma unroll
    for (int t = 0; t < 4; ++t) {
      float p0 = __builtin_amdgcn_exp2f(sc[t][0] - m_new);
      float p1 = __builtin_amdgcn_exp2f(sc[t][1] - m_new);
      float p2 = __builtin_amdgcn_exp2f(sc[t][2] - m_new);
      float p3 = __builtin_amdgcn_exp2f(sc[t][3] - m_new);
      s += (p0 + p1) + (p2 + p3);
      pk2[t][0] = pack2bf(p0, p1);
      pk2[t][1] = pack2bf(p2, p3);
    }
    s += __shfl_xor(s, 16, 64);
    s += __shfl_xor(s, 32, 64);
    lsum = lsum * alpha + s;
#pragma unroll
    for (int jn = 0; jn < 4; ++jn)
#pragma unroll
      for (int r = 0; r < 4; ++r) o[jn][r] *= alpha;

    // ---- P -> LDS [q][key]: lane writes its 4 consecutive keys per tile (b64)
#pragma unroll
    for (int t = 0; t < 4; ++t) {
      uint2 w; w.x = pk2[t][0]; w.y = pk2[t][1];
      *(uint2*)(psw + l15 * 72 + 16 * t + 4 * l4) = w;
    }
    // B-frag read (same wave, program-ordered: no barrier needed)
    short8 pf0 = *(const short8*)(psw + l15 * 72 + l4 * 8);
    short8 pf1 = *(const short8*)(psw + l15 * 72 + 32 + l4 * 8);

    // ---- O^T += V^T . P^T : A[m=d][k=key] from Vt, B[n=q][k=key] = P
#pragma unroll
    for (int jn = 0; jn < 4; ++jn) {
      const short* pvt = Vt + (jn * 16 + l15) * 72 + l4 * 8;
      short8 v0 = *(const short8*)pvt;
      short8 v1 = *(const short8*)(pvt + 32);
      o[jn] = __builtin_amdgcn_mfma_f32_16x16x32_bf16(v0, pf0, o[jn], 0, 0, 0);
      o[jn] = __builtin_amdgcn_mfma_f32_16x16x32_bf16(v1, pf1, o[jn], 0, 0, 0);
    }
  }

  // ---- epilogue: lane owns q row (qt*4+wave, inner l15); d = 16jn+4l4+r
  const float inv = 1.0f / lsum;
  unsigned short* so = (unsigned short*)sa + (size_t)(bh * 128 + qt * 4 + wave) * 1024;
#pragma unroll
  for (int jn = 0; jn < 4; ++jn) {
    uint2 w;
    w.x = pack2bf(o[jn][0] * inv, o[jn][1] * inv);
    w.y = pack2bf(o[jn][2] * inv, o[jn][3] * inv);
    *(uint2*)(so + l15 * 64 + jn * 16 + l4 * 4) = w;
  }
}

extern "C" void kernel_launch(void* const* d_in, const int* in_sizes, int n_in,
                              void* d_out, int out_size, void* d_ws, size_t ws_size,
                              hipStream_t stream)
{
  const void* x_raw    = d_in[0];  // [4,2048,1024]
  const void* Wqkv_raw = d_in[1];  // [1024,3072]
  const void* bqkv_raw = d_in[2];  // [3072]
  const void* Wout_raw = d_in[3];  // [1024,1024]
  const void* bout_raw = d_in[4];  // [1024]

  char* ws = (char*)d_ws;
  int*  flag   = (int*)ws;                                  //   256 B
  bf16* xb     = (bf16*)(ws + 256);                         //  16 MiB (8192*1024)
  bf16* wqkvT  = xb + (size_t)8192 * 1024;                  //   6 MiB (3072*1024, [N][K])
  bf16* bqkvb  = wqkvT + (size_t)3072 * 1024;               //   6 KiB
  bf16* woutT  = bqkvb + 4096;                              //   2 MiB (1024*1024, [N][K])
  bf16* boutb  = woutT + (size_t)1024 * 1024;               //   2 KiB
  bf16* qkv    = boutb + 4096;                              //  48 MiB (8192*3072)
  bf16* sa     = qkv + (size_t)8192 * 3072;                 //  16 MiB (8192*1024)

  detect_kernel<<<1, 64, 0, stream>>>((const unsigned int*)x_raw, flag);

  convert_kernel<<<(8192 * 1024 / 8 + 255) / 256, 256, 0, stream>>>(x_raw, xb, 8192 * 1024 / 8, flag);
  convert_bias_qkv<<<12, 256, 0, stream>>>(bqkv_raw, bqkvb, flag);
  convert_kernel<<<1, 256, 0, stream>>>(bout_raw, boutb, 1024 / 8, flag);
  transpose_bf16<<<dim3(3072 / 32, 1024 / 32), 256, 0, stream>>>(Wqkv_raw, wqkvT, 1024, 3072, flag, 1);
  transpose_bf16<<<dim3(1024 / 32, 1024 / 32), 256, 0, stream>>>(Wout_raw, woutT, 1024, 1024, flag, 0);

  // 1) qkv = x @ W_qkv + b_qkv   (M=8192, N=3072, K=1024); Q cols pre-scaled
  gemm_mfma<<<dim3(3072 / 128, 8192 / 128), 256, 0, stream>>>(
      xb, wqkvT, bqkvb, qkv, 8192, 3072, 1024, 0, flag);
  // 2) MFMA flash attention: one q-tile per block, 8 blocks/CU
  attn_mfma<<<dim3(64, 32), 256, 0, stream>>>(qkv, sa);
  // 3) out = sa @ W_out + b_out  (M=8192, N=1024, K=1024)
  gemm_mfma<<<dim3(1024 / 128, 8192 / 128), 256, 0, stream>>>(
      sa, woutT, boutb, d_out, 8192, 1024, 1024, 1, flag);
}

// Round 3
// 496.497 us; speedup vs baseline: 1.0084x; 1.0084x over previous
//
#include <hip/hip_runtime.h>
#include <hip/hip_bf16.h>

using bf16 = __hip_bfloat16;

typedef __attribute__((ext_vector_type(8))) short short8;   // 8 x bf16 (4 VGPRs)
typedef __attribute__((ext_vector_type(4))) float f32x4;    // MFMA C/D

// MaskedMSA: B=4, S=2048, E=1024, HIDDEN=1024, HEADS=16
// Reference reshape mixes seq/hidden: with t=16u+r (u<128, r<16):
//   q[b,h,t,e] = qkv[b, 128h+u, 192r +   0 + e]
//   k[b,h,t,e] = qkv[b, 128h+u, 192r +  64 + e]
//   v[b,h,t,e] = qkv[b, 128h+u, 192r + 128 + e]
// Output: sa[b,h,t,e] -> out row 128h+u, col 64r+e. Causal mask on permuted t.
// Q columns of W_qkv/b_qkv are pre-scaled by scale*log2(e): exp2-domain scores.
//
// R1 lesson: pipelining the kt-loop was neutral -> latency chain per iter
// (~12K cyc) is the cost, not barrier placement.
// R2 lesson: launch_bounds(256,8) forced <=64 unified regs -> massive spill
// (918 MB scratch traffic, 295us). True demand ~85-90; occupancy can't rise.
// R3: amortize instead -- TWO adjacent q-tiles per block (2x MFMA/softmax work
// per identical latency chain). K loads / V staging / barriers shared; Ps LDS
// reused sequentially (same-wave program order). Regs ~120 <= 128 budget.

#define CEXP 0.03188127742677263f  // (2*1024)^-0.5 * log2(e)

__device__ __forceinline__ unsigned short f2bf(float v) {
  bf16 h = __float2bfloat16(v);
  return *(unsigned short*)&h;
}
__device__ __forceinline__ unsigned int pack2bf(float a, float b) {
  return (unsigned int)f2bf(a) | ((unsigned int)f2bf(b) << 16);
}

// async global->LDS, 16B per lane; LDS dest = wave-uniform base + lane*16.
__device__ __forceinline__ void gload_lds16(const void* g, void* lds) {
  __builtin_amdgcn_global_load_lds(
      (const __attribute__((address_space(1))) unsigned int*)(g),
      (__attribute__((address_space(3))) unsigned int*)(lds), 16, 0, 0);
}

// ---- dtype detect: flag=1 if fp32 I/O, flag=0 if bf16 I/O.
__global__ void detect_kernel(const unsigned int* __restrict__ x, int* __restrict__ flag) {
  unsigned int w = x[threadIdx.x];
  unsigned int e = (w >> 7) & 0xFF;
  bool inband = (e >= 96 && e <= 133);
  unsigned long long m = __ballot(inband);
  if (threadIdx.x == 0) flag[0] = (__popcll(m) >= 48) ? 0 : 1;
}

// ---- convert n8*8 elements to bf16 (copy if already bf16)
__global__ __launch_bounds__(256) void convert_kernel(
    const void* __restrict__ src, bf16* __restrict__ dst, int n8,
    const int* __restrict__ flag) {
  int i = blockIdx.x * 256 + threadIdx.x;
  if (i >= n8) return;
  uint4 outv;
  if (*flag) {
    const float4* s = (const float4*)src + (size_t)i * 2;
    float4 a = s[0], b = s[1];
    outv.x = pack2bf(a.x, a.y);
    outv.y = pack2bf(a.z, a.w);
    outv.z = pack2bf(b.x, b.y);
    outv.w = pack2bf(b.z, b.w);
  } else {
    outv = ((const uint4*)src)[i];
  }
  ((uint4*)dst)[i] = outv;
}

// ---- b_qkv convert with Q-column pre-scale (cols with (i%192)<64)
__global__ void convert_bias_qkv(const void* __restrict__ src, bf16* __restrict__ dst,
                                 const int* __restrict__ flag) {
  int i = blockIdx.x * 256 + threadIdx.x;
  if (i >= 3072) return;
  float v = (*flag) ? ((const float*)src)[i]
                    : __bfloat162float(((const bf16*)src)[i]);
  if ((i % 192) < 64) v *= CEXP;
  dst[i] = __float2bfloat16(v);
}

// ---- transpose src[R][C] -> dst[C][R] (bf16 out); qscale: scale rows n with
// (n%192)<64 by CEXP (W_qkv Q columns -> exp2 domain).
__global__ __launch_bounds__(256) void transpose_bf16(
    const void* __restrict__ src, bf16* __restrict__ dst, int R, int Cc,
    const int* __restrict__ flag, int qscale) {
  __shared__ float tile[32][33];
  const int c0 = blockIdx.x * 32, r0 = blockIdx.y * 32;
  const int tx = threadIdx.x & 31, ty = threadIdx.x >> 5;  // 32 x 8
  const bool f32 = (*flag != 0);
#pragma unroll
  for (int it = 0; it < 4; ++it) {
    int r = ty + it * 8;
    float v;
    if (f32) v = ((const float*)src)[(size_t)(r0 + r) * Cc + c0 + tx];
    else     v = __bfloat162float(((const bf16*)src)[(size_t)(r0 + r) * Cc + c0 + tx]);
    tile[r][tx] = v;
  }
  __syncthreads();
#pragma unroll
  for (int it = 0; it < 4; ++it) {
    int r = ty + it * 8;   // dst row n = c0 + r
    float vv = tile[tx][r];
    if (qscale && (((c0 + r) % 192) < 64)) vv *= CEXP;
    dst[(size_t)(c0 + r) * R + r0 + tx] = __float2bfloat16(vv);
  }
}

// ---------------- MFMA GEMM (m97 pattern): C[M,N] = A[M,K] @ BT[N,K]^T + bias
__global__ __launch_bounds__(256) void gemm_mfma(
    const bf16* __restrict__ A, const bf16* __restrict__ BT,
    const bf16* __restrict__ bias, void* __restrict__ C,
    int M, int N, int K, int store_mode, const int* __restrict__ flag)
{
  __shared__ alignas(16) unsigned short As[128 * 32];  // [m][k] contiguous
  __shared__ alignas(16) unsigned short Bs[128 * 32];  // [n][k] contiguous
  const bool store_f32 = store_mode && (*flag != 0);
  const int tid = threadIdx.x;
  const int wave = tid >> 6, lane = tid & 63;
  const int l15 = lane & 15, l4 = lane >> 4;
  const int m0 = blockIdx.y * 128, n0 = blockIdx.x * 128;
  const int wm = (wave & 1) * 64, wn = (wave >> 1) * 64;

  const int srow = wave * 32 + (lane >> 2);
  const int skv = (lane & 3) * 8;
  const bf16* ga = A + (size_t)(m0 + srow) * K + skv;
  const bf16* gb = BT + (size_t)(n0 + srow) * K + skv;
  unsigned short* la = As + (wave * 32) * 32;
  unsigned short* lb = Bs + (wave * 32) * 32;

  f32x4 acc[4][4] = {};

  for (int k0 = 0; k0 < K; k0 += 32) {
    __syncthreads();
    gload_lds16(ga, la);
    gload_lds16(ga + (size_t)16 * K, la + 16 * 32);
    gload_lds16(gb, lb);
    gload_lds16(gb + (size_t)16 * K, lb + 16 * 32);
    ga += 32; gb += 32;
    __syncthreads();

    short8 af[4], bfr[4];
#pragma unroll
    for (int i = 0; i < 4; ++i) {
      af[i]  = *(const short8*)(As + (wm + i * 16 + l15) * 32 + l4 * 8);
      bfr[i] = *(const short8*)(Bs + (wn + i * 16 + l15) * 32 + l4 * 8);
    }
#pragma unroll
    for (int i = 0; i < 4; ++i)
#pragma unroll
      for (int j = 0; j < 4; ++j)
        acc[i][j] = __builtin_amdgcn_mfma_f32_16x16x32_bf16(af[i], bfr[j], acc[i][j], 0, 0, 0);
  }

#pragma unroll
  for (int j = 0; j < 4; ++j) {
    const int n = n0 + wn + j * 16 + l15;
    const float bv = __bfloat162float(bias[n]);
#pragma unroll
    for (int i = 0; i < 4; ++i) {
#pragma unroll
      for (int r = 0; r < 4; ++r) {
        const int mrow = m0 + wm + i * 16 + l4 * 4 + r;
        const float v = acc[i][j][r] + bv;
        if (store_f32) ((float*)C)[(size_t)mrow * N + n] = v;
        else           ((bf16*)C)[(size_t)mrow * N + n] = __float2bfloat16(v);
      }
    }
  }
}

// ---------------- MFMA flash attention, transposed (S^T / O^T) formulation.
// grid (64 bh, 16 p); block owns ADJACENT q-tiles qtA=2p', qtB=2p'+1
// (p' = 15-p: longest first). Per wave: 16 q rows per tile (q = l15);
// S^T = mfma(K, Q) -> lane-local softmax; P -> LDS (reused buffer, sequential
// per tile); O^T = mfma(Vt, P). V staged [d][key] in LDS, shared by both tiles.
__global__ __launch_bounds__(256, 4) void attn_mfma(const bf16* __restrict__ qkv,
                                                    bf16* __restrict__ sa)
{
  __shared__ alignas(16) short Vt[64 * 72];       // [d][key], stride 72 (144B, 16B-mult)
  __shared__ alignas(16) short Ps[4][16 * 72];    // per-wave [q][key], stride 72
  const int tid = threadIdx.x;
  const int bh = blockIdx.x;
  const int qp = 15 - blockIdx.y;                 // longest blocks dispatch first
  const int qtA = 2 * qp, qtB = 2 * qp + 1;
  const size_t base = (size_t)bh * 393216;        // (bh*128) * 3072
  const int wave = tid >> 6;
  const int lane = tid & 63;
  const int l15 = lane & 15;
  const int l4 = lane >> 4;
  const unsigned short* qk = (const unsigned short*)qkv;

  // V staging ownership: this thread owns key=tid&63, d-vectors dv0 and dv0+4
  const int key = tid & 63;
  const int dv0 = tid >> 6;
  const unsigned short* vbase =
      qk + base + (size_t)(key >> 4) * 3072 + (key & 15) * 192 + 128;
  short* psw = &Ps[wave][0];

  // Q B-frags: B[n=q(l15)][k=d(l4*8+j)], one row per wave per tile
  const unsigned short* pqA = qk + base + (size_t)(qtA * 4 + wave) * 3072 + l15 * 192 + l4 * 8;
  const unsigned short* pqB = qk + base + (size_t)(qtB * 4 + wave) * 3072 + l15 * 192 + l4 * 8;
  short8 qfA0 = *(const short8*)pqA;
  short8 qfA1 = *(const short8*)(pqA + 32);
  short8 qfB0 = *(const short8*)pqB;
  short8 qfB1 = *(const short8*)(pqB + 32);
  // V regs for kt=0
  short8 vn0 = *(const short8*)(vbase + dv0 * 8);
  short8 vn1 = *(const short8*)(vbase + (dv0 + 4) * 8);

  f32x4 oA[4] = {}, oB[4] = {};    // O^T: col=q(l15), row=d(16jn+4l4+r)
  float mA = -__builtin_inff(), lA = 0.f;
  float mB = -__builtin_inff(), lB = 0.f;

  for (int kt = 0; kt <= qtB; ++kt) {
    const bool doA = (kt <= qtA);  // block-uniform

    // K A-frags (shared by both tiles): A[m=key(l15)][k=d]
    short8 kf0[4], kf1[4];
#pragma unroll
    for (int t = 0; t < 4; ++t) {
      const unsigned short* pk =
          qk + base + (size_t)(kt * 4 + t) * 3072 + l15 * 192 + 64 + l4 * 8;
      kf0[t] = *(const short8*)pk;
      kf1[t] = *(const short8*)(pk + 32);
    }
    // prefetch next V tile
    short8 vx0 = vn0, vx1 = vn1;
    if (kt < qtB) {
      const unsigned short* pv = vbase + (size_t)(kt + 1) * 12288;  // 4*3072
      vn0 = *(const short8*)(pv + dv0 * 8);
      vn1 = *(const short8*)(pv + (dv0 + 4) * 8);
    }
    __syncthreads();               // prior PV reads of Vt done (drains loads)
#pragma unroll
    for (int jj = 0; jj < 8; ++jj) {
      Vt[(dv0 * 8 + jj) * 72 + key] = vx0[jj];
      Vt[((dv0 + 4) * 8 + jj) * 72 + key] = vx1[jj];
    }
    __syncthreads();               // Vt ready

    // ---- S^T = K . Q^T for both tiles: col=q(l15), row=key_local(16t+4l4+r)
    f32x4 scA[4], scB[4];
#pragma unroll
    for (int t = 0; t < 4; ++t) {
      f32x4 c = {};
      c = __builtin_amdgcn_mfma_f32_16x16x32_bf16(kf0[t], qfB0, c, 0, 0, 0);
      c = __builtin_amdgcn_mfma_f32_16x16x32_bf16(kf1[t], qfB1, c, 0, 0, 0);
      scB[t] = c;
    }
    if (doA) {
#pragma unroll
      for (int t = 0; t < 4; ++t) {
        f32x4 c = {};
        c = __builtin_amdgcn_mfma_f32_16x16x32_bf16(kf0[t], qfA0, c, 0, 0, 0);
        c = __builtin_amdgcn_mfma_f32_16x16x32_bf16(kf1[t], qfA1, c, 0, 0, 0);
        scA[t] = c;
      }
      if (kt == qtA) {             // wave-uniform diag branch (tile A)
        const int qloc = wave * 16 + l15;
#pragma unroll
        for (int t = 0; t < 4; ++t)
#pragma unroll
          for (int r = 0; r < 4; ++r)
            if (16 * t + 4 * l4 + r > qloc) scA[t][r] = -__builtin_inff();
      }
    }
    if (kt == qtB) {               // diag for tile B (last iteration)
      const int qloc = wave * 16 + l15;
#pragma unroll
      for (int t = 0; t < 4; ++t)
#pragma unroll
        for (int r = 0; r < 4; ++r)
          if (16 * t + 4 * l4 + r > qloc) scB[t][r] = -__builtin_inff();
    }

    // ---- softmax A and B (independent chains -> ILP hides shuffle latency)
    unsigned int pkA[4][2], pkB[4][2];
    if (doA) {
      float mx = -__builtin_inff();
#pragma unroll
      for (int t = 0; t < 4; ++t)
#pragma unroll
        for (int r = 0; r < 4; ++r) mx = fmaxf(mx, scA[t][r]);
      mx = fmaxf(mx, __shfl_xor(mx, 16, 64));
      mx = fmaxf(mx, __shfl_xor(mx, 32, 64));
      const float m_new = fmaxf(mA, mx);
      const float alpha = __builtin_amdgcn_exp2f(mA - m_new);
      mA = m_new;
      float s = 0.f;
#pragma unroll
      for (int t = 0; t < 4; ++t) {
        float p0 = __builtin_amdgcn_exp2f(scA[t][0] - m_new);
        float p1 = __builtin_amdgcn_exp2f(scA[t][1] - m_new);
        float p2 = __builtin_amdgcn_exp2f(scA[t][2] - m_new);
        float p3 = __builtin_amdgcn_exp2f(scA[t][3] - m_new);
        s += (p0 + p1) + (p2 + p3);
        pkA[t][0] = pack2bf(p0, p1);
        pkA[t][1] = pack2bf(p2, p3);
      }
      s += __shfl_xor(s, 16, 64);
      s += __shfl_xor(s, 32, 64);
      lA = lA * alpha + s;
#pragma unroll
      for (int jn = 0; jn < 4; ++jn)
#pragma unroll
        for (int r = 0; r < 4; ++r) oA[jn][r] *= alpha;
    }
    {
      float mx = -__builtin_inff();
#pragma unroll
      for (int t = 0; t < 4; ++t)
#pragma unroll
        for (int r = 0; r < 4; ++r) mx = fmaxf(mx, scB[t][r]);
      mx = fmaxf(mx, __shfl_xor(mx, 16, 64));
      mx = fmaxf(mx, __shfl_xor(mx, 32, 64));
      const float m_new = fmaxf(mB, mx);
      const float alpha = __builtin_amdgcn_exp2f(mB - m_new);
      mB = m_new;
      float s = 0.f;
#pragma unroll
      for (int t = 0; t < 4; ++t) {
        float p0 = __builtin_amdgcn_exp2f(scB[t][0] - m_new);
        float p1 = __builtin_amdgcn_exp2f(scB[t][1] - m_new);
        float p2 = __builtin_amdgcn_exp2f(scB[t][2] - m_new);
        float p3 = __builtin_amdgcn_exp2f(scB[t][3] - m_new);
        s += (p0 + p1) + (p2 + p3);
        pkB[t][0] = pack2bf(p0, p1);
        pkB[t][1] = pack2bf(p2, p3);
      }
      s += __shfl_xor(s, 16, 64);
      s += __shfl_xor(s, 32, 64);
      lB = lB * alpha + s;
#pragma unroll
      for (int jn = 0; jn < 4; ++jn)
#pragma unroll
        for (int r = 0; r < 4; ++r) oB[jn][r] *= alpha;
    }

    // ---- P_A -> LDS -> pfA -> PV_A (Ps reused: same-wave program order)
    if (doA) {
#pragma unroll
      for (int t = 0; t < 4; ++t) {
        uint2 w; w.x = pkA[t][0]; w.y = pkA[t][1];
        *(uint2*)(psw + l15 * 72 + 16 * t + 4 * l4) = w;
      }
      short8 pf0 = *(const short8*)(psw + l15 * 72 + l4 * 8);
      short8 pf1 = *(const short8*)(psw + l15 * 72 + 32 + l4 * 8);
#pragma unroll
      for (int jn = 0; jn < 4; ++jn) {
        const short* pvt = Vt + (jn * 16 + l15) * 72 + l4 * 8;
        short8 v0 = *(const short8*)pvt;
        short8 v1 = *(const short8*)(pvt + 32);
        oA[jn] = __builtin_amdgcn_mfma_f32_16x16x32_bf16(v0, pf0, oA[jn], 0, 0, 0);
        oA[jn] = __builtin_amdgcn_mfma_f32_16x16x32_bf16(v1, pf1, oA[jn], 0, 0, 0);
      }
    }
    // ---- P_B -> LDS -> pfB -> PV_B
    {
#pragma unroll
      for (int t = 0; t < 4; ++t) {
        uint2 w; w.x = pkB[t][0]; w.y = pkB[t][1];
        *(uint2*)(psw + l15 * 72 + 16 * t + 4 * l4) = w;
      }
      short8 pf0 = *(const short8*)(psw + l15 * 72 + l4 * 8);
      short8 pf1 = *(const short8*)(psw + l15 * 72 + 32 + l4 * 8);
#pragma unroll
      for (int jn = 0; jn < 4; ++jn) {
        const short* pvt = Vt + (jn * 16 + l15) * 72 + l4 * 8;
        short8 v0 = *(const short8*)pvt;
        short8 v1 = *(const short8*)(pvt + 32);
        oB[jn] = __builtin_amdgcn_mfma_f32_16x16x32_bf16(v0, pf0, oB[jn], 0, 0, 0);
        oB[jn] = __builtin_amdgcn_mfma_f32_16x16x32_bf16(v1, pf1, oB[jn], 0, 0, 0);
      }
    }
  }

  // ---- epilogue: lane owns q row (qt*4+wave, inner l15); d = 16jn+4l4+r
  {
    const float inv = 1.0f / lA;
    unsigned short* so = (unsigned short*)sa + (size_t)(bh * 128 + qtA * 4 + wave) * 1024;
#pragma unroll
    for (int jn = 0; jn < 4; ++jn) {
      uint2 w;
      w.x = pack2bf(oA[jn][0] * inv, oA[jn][1] * inv);
      w.y = pack2bf(oA[jn][2] * inv, oA[jn][3] * inv);
      *(uint2*)(so + l15 * 64 + jn * 16 + l4 * 4) = w;
    }
  }
  {
    const float inv = 1.0f / lB;
    unsigned short* so = (unsigned short*)sa + (size_t)(bh * 128 + qtB * 4 + wave) * 1024;
#pragma unroll
    for (int jn = 0; jn < 4; ++jn) {
      uint2 w;
      w.x = pack2bf(oB[jn][0] * inv, oB[jn][1] * inv);
      w.y = pack2bf(oB[jn][2] * inv, oB[jn][3] * inv);
      *(uint2*)(so + l15 * 64 + jn * 16 + l4 * 4) = w;
    }
  }
}

extern "C" void kernel_launch(void* const* d_in, const int* in_sizes, int n_in,
                              void* d_out, int out_size, void* d_ws, size_t ws_size,
                              hipStream_t stream)
{
  const void* x_raw    = d_in[0];  // [4,2048,1024]
  const void* Wqkv_raw = d_in[1];  // [1024,3072]
  const void* bqkv_raw = d_in[2];  // [3072]
  const void* Wout_raw = d_in[3];  // [1024,1024]
  const void* bout_raw = d_in[4];  // [1024]

  char* ws = (char*)d_ws;
  int*  flag   = (int*)ws;                                  //   256 B
  bf16* xb     = (bf16*)(ws + 256);                         //  16 MiB (8192*1024)
  bf16* wqkvT  = xb + (size_t)8192 * 1024;                  //   6 MiB (3072*1024, [N][K])
  bf16* bqkvb  = wqkvT + (size_t)3072 * 1024;               //   6 KiB
  bf16* woutT  = bqkvb + 4096;                              //   2 MiB (1024*1024, [N][K])
  bf16* boutb  = woutT + (size_t)1024 * 1024;               //   2 KiB
  bf16* qkv    = boutb + 4096;                              //  48 MiB (8192*3072)
  bf16* sa     = qkv + (size_t)8192 * 3072;                 //  16 MiB (8192*1024)

  detect_kernel<<<1, 64, 0, stream>>>((const unsigned int*)x_raw, flag);

  convert_kernel<<<(8192 * 1024 / 8 + 255) / 256, 256, 0, stream>>>(x_raw, xb, 8192 * 1024 / 8, flag);
  convert_bias_qkv<<<12, 256, 0, stream>>>(bqkv_raw, bqkvb, flag);
  convert_kernel<<<1, 256, 0, stream>>>(bout_raw, boutb, 1024 / 8, flag);
  transpose_bf16<<<dim3(3072 / 32, 1024 / 32), 256, 0, stream>>>(Wqkv_raw, wqkvT, 1024, 3072, flag, 1);
  transpose_bf16<<<dim3(1024 / 32, 1024 / 32), 256, 0, stream>>>(Wout_raw, woutT, 1024, 1024, flag, 0);

  // 1) qkv = x @ W_qkv + b_qkv   (M=8192, N=3072, K=1024); Q cols pre-scaled
  gemm_mfma<<<dim3(3072 / 128, 8192 / 128), 256, 0, stream>>>(
      xb, wqkvT, bqkvb, qkv, 8192, 3072, 1024, 0, flag);
  // 2) MFMA flash attention: two adjacent q-tiles per block (amortized chain)
  attn_mfma<<<dim3(64, 16), 256, 0, stream>>>(qkv, sa);
  // 3) out = sa @ W_out + b_out  (M=8192, N=1024, K=1024)
  gemm_mfma<<<dim3(1024 / 128, 8192 / 128), 256, 0, stream>>>(
      sa, woutT, boutb, d_out, 8192, 1024, 1024, 1, flag);
}

// Round 4
// 463.026 us; speedup vs baseline: 1.0813x; 1.0723x over previous
//
#include <hip/hip_runtime.h>
#include <hip/hip_bf16.h>

using bf16 = __hip_bfloat16;

typedef __attribute__((ext_vector_type(8))) short short8;   // 8 x bf16 (4 VGPRs)
typedef __attribute__((ext_vector_type(4))) float f32x4;    // MFMA C/D

// MaskedMSA: B=4, S=2048, E=1024, HIDDEN=1024, HEADS=16
// Reference reshape mixes seq/hidden: with t=16u+r (u<128, r<16):
//   q[b,h,t,e] = qkv[b, 128h+u, 192r +   0 + e]
//   k[b,h,t,e] = qkv[b, 128h+u, 192r +  64 + e]
//   v[b,h,t,e] = qkv[b, 128h+u, 192r + 128 + e]
// Output: sa[b,h,t,e] -> out row 128h+u, col 64r+e. Causal mask on permuted t.
// Q columns of W_qkv/b_qkv are pre-scaled by scale*log2(e): exp2-domain scores.
//
// R1 lesson: pipelining the kt-loop was neutral -> per-iter latency chain is
// the cost, not barrier placement.
// R2/R3 lesson: both more-blocks (launch_bounds 8) and more-work-per-wave
// (2 q-tiles) blow the 128-reg envelope -> catastrophic spill. One tile of
// state per wave is the budget.
// R4: remove the reason barriers exist at all. V is pre-transposed ONCE into
// global Vtg[bh][d][key] (16 MB, L2-resident per bh); PV A-frags become plain
// b128 global loads. attn_mfma has NO __syncthreads, fully independent waves,
// un-paired q-tiles (grid 64x32, longest first).

#define CEXP 0.03188127742677263f  // (2*1024)^-0.5 * log2(e)

__device__ __forceinline__ unsigned short f2bf(float v) {
  bf16 h = __float2bfloat16(v);
  return *(unsigned short*)&h;
}
__device__ __forceinline__ unsigned int pack2bf(float a, float b) {
  return (unsigned int)f2bf(a) | ((unsigned int)f2bf(b) << 16);
}

// async global->LDS, 16B per lane; LDS dest = wave-uniform base + lane*16.
__device__ __forceinline__ void gload_lds16(const void* g, void* lds) {
  __builtin_amdgcn_global_load_lds(
      (const __attribute__((address_space(1))) unsigned int*)(g),
      (__attribute__((address_space(3))) unsigned int*)(lds), 16, 0, 0);
}

// ---- dtype detect: flag=1 if fp32 I/O, flag=0 if bf16 I/O.
__global__ void detect_kernel(const unsigned int* __restrict__ x, int* __restrict__ flag) {
  unsigned int w = x[threadIdx.x];
  unsigned int e = (w >> 7) & 0xFF;
  bool inband = (e >= 96 && e <= 133);
  unsigned long long m = __ballot(inband);
  if (threadIdx.x == 0) flag[0] = (__popcll(m) >= 48) ? 0 : 1;
}

// ---- convert n8*8 elements to bf16 (copy if already bf16)
__global__ __launch_bounds__(256) void convert_kernel(
    const void* __restrict__ src, bf16* __restrict__ dst, int n8,
    const int* __restrict__ flag) {
  int i = blockIdx.x * 256 + threadIdx.x;
  if (i >= n8) return;
  uint4 outv;
  if (*flag) {
    const float4* s = (const float4*)src + (size_t)i * 2;
    float4 a = s[0], b = s[1];
    outv.x = pack2bf(a.x, a.y);
    outv.y = pack2bf(a.z, a.w);
    outv.z = pack2bf(b.x, b.y);
    outv.w = pack2bf(b.z, b.w);
  } else {
    outv = ((const uint4*)src)[i];
  }
  ((uint4*)dst)[i] = outv;
}

// ---- b_qkv convert with Q-column pre-scale (cols with (i%192)<64)
__global__ void convert_bias_qkv(const void* __restrict__ src, bf16* __restrict__ dst,
                                 const int* __restrict__ flag) {
  int i = blockIdx.x * 256 + threadIdx.x;
  if (i >= 3072) return;
  float v = (*flag) ? ((const float*)src)[i]
                    : __bfloat162float(((const bf16*)src)[i]);
  if ((i % 192) < 64) v *= CEXP;
  dst[i] = __float2bfloat16(v);
}

// ---- transpose src[R][C] -> dst[C][R] (bf16 out); qscale: scale rows n with
// (n%192)<64 by CEXP (W_qkv Q columns -> exp2 domain).
__global__ __launch_bounds__(256) void transpose_bf16(
    const void* __restrict__ src, bf16* __restrict__ dst, int R, int Cc,
    const int* __restrict__ flag, int qscale) {
  __shared__ float tile[32][33];
  const int c0 = blockIdx.x * 32, r0 = blockIdx.y * 32;
  const int tx = threadIdx.x & 31, ty = threadIdx.x >> 5;  // 32 x 8
  const bool f32 = (*flag != 0);
#pragma unroll
  for (int it = 0; it < 4; ++it) {
    int r = ty + it * 8;
    float v;
    if (f32) v = ((const float*)src)[(size_t)(r0 + r) * Cc + c0 + tx];
    else     v = __bfloat162float(((const bf16*)src)[(size_t)(r0 + r) * Cc + c0 + tx]);
    tile[r][tx] = v;
  }
  __syncthreads();
#pragma unroll
  for (int it = 0; it < 4; ++it) {
    int r = ty + it * 8;   // dst row n = c0 + r
    float vv = tile[tx][r];
    if (qscale && (((c0 + r) % 192) < 64)) vv *= CEXP;
    dst[(size_t)(c0 + r) * R + r0 + tx] = __float2bfloat16(vv);
  }
}

// ---- V pre-transpose: Vtg[bh][d][key] (d<64, key<2048) from permuted qkv.
// One block = (bh, 64-key tile). 16 MB total, runs once after the QKV GEMM.
__global__ __launch_bounds__(256) void transpose_v(const bf16* __restrict__ qkv,
                                                   bf16* __restrict__ vtg)
{
  __shared__ short tile[64][72];
  const int bh = blockIdx.x;
  const int k0 = blockIdx.y * 64;
  const unsigned short* qk = (const unsigned short*)qkv + (size_t)bh * 393216;
  const int key = threadIdx.x & 63;
  const int dv = threadIdx.x >> 6;      // 0..3 -> d-range dv*16
  const int gk = k0 + key;
  const unsigned short* src =
      qk + (size_t)(gk >> 4) * 3072 + (gk & 15) * 192 + 128 + dv * 16;
  *(short8*)&tile[key][dv * 16] = *(const short8*)src;
  *(short8*)&tile[key][dv * 16 + 8] = *(const short8*)(src + 8);
  __syncthreads();
  const int d = threadIdx.x & 63;
  const int kv = threadIdx.x >> 6;      // 0..3 -> key-range kv*16
  unsigned short* dst =
      (unsigned short*)vtg + ((size_t)bh * 64 + d) * 2048 + k0 + kv * 16;
  short8 a, b;
#pragma unroll
  for (int j = 0; j < 8; ++j) {
    a[j] = tile[kv * 16 + j][d];
    b[j] = tile[kv * 16 + 8 + j][d];
  }
  *(short8*)dst = a;
  *(short8*)(dst + 8) = b;
}

// ---------------- MFMA GEMM (m97 pattern): C[M,N] = A[M,K] @ BT[N,K]^T + bias
__global__ __launch_bounds__(256) void gemm_mfma(
    const bf16* __restrict__ A, const bf16* __restrict__ BT,
    const bf16* __restrict__ bias, void* __restrict__ C,
    int M, int N, int K, int store_mode, const int* __restrict__ flag)
{
  __shared__ alignas(16) unsigned short As[128 * 32];  // [m][k] contiguous
  __shared__ alignas(16) unsigned short Bs[128 * 32];  // [n][k] contiguous
  const bool store_f32 = store_mode && (*flag != 0);
  const int tid = threadIdx.x;
  const int wave = tid >> 6, lane = tid & 63;
  const int l15 = lane & 15, l4 = lane >> 4;
  const int m0 = blockIdx.y * 128, n0 = blockIdx.x * 128;
  const int wm = (wave & 1) * 64, wn = (wave >> 1) * 64;

  const int srow = wave * 32 + (lane >> 2);
  const int skv = (lane & 3) * 8;
  const bf16* ga = A + (size_t)(m0 + srow) * K + skv;
  const bf16* gb = BT + (size_t)(n0 + srow) * K + skv;
  unsigned short* la = As + (wave * 32) * 32;
  unsigned short* lb = Bs + (wave * 32) * 32;

  f32x4 acc[4][4] = {};

  for (int k0 = 0; k0 < K; k0 += 32) {
    __syncthreads();
    gload_lds16(ga, la);
    gload_lds16(ga + (size_t)16 * K, la + 16 * 32);
    gload_lds16(gb, lb);
    gload_lds16(gb + (size_t)16 * K, lb + 16 * 32);
    ga += 32; gb += 32;
    __syncthreads();

    short8 af[4], bfr[4];
#pragma unroll
    for (int i = 0; i < 4; ++i) {
      af[i]  = *(const short8*)(As + (wm + i * 16 + l15) * 32 + l4 * 8);
      bfr[i] = *(const short8*)(Bs + (wn + i * 16 + l15) * 32 + l4 * 8);
    }
#pragma unroll
    for (int i = 0; i < 4; ++i)
#pragma unroll
      for (int j = 0; j < 4; ++j)
        acc[i][j] = __builtin_amdgcn_mfma_f32_16x16x32_bf16(af[i], bfr[j], acc[i][j], 0, 0, 0);
  }

#pragma unroll
  for (int j = 0; j < 4; ++j) {
    const int n = n0 + wn + j * 16 + l15;
    const float bv = __bfloat162float(bias[n]);
#pragma unroll
    for (int i = 0; i < 4; ++i) {
#pragma unroll
      for (int r = 0; r < 4; ++r) {
        const int mrow = m0 + wm + i * 16 + l4 * 4 + r;
        const float v = acc[i][j][r] + bv;
        if (store_f32) ((float*)C)[(size_t)mrow * N + n] = v;
        else           ((bf16*)C)[(size_t)mrow * N + n] = __float2bfloat16(v);
      }
    }
  }
}

// ---------------- MFMA flash attention, transposed (S^T / O^T), BARRIER-FREE.
// grid (64 bh, 32 y); block owns q-tile qt = 31-y (longest first).
// Per wave: 16 q rows (q = l15); S^T = mfma(K, Q) -> lane-local softmax;
// P -> per-wave LDS roundtrip (program-ordered, no barrier);
// O^T = mfma(Vt, P) with V frags loaded straight from pre-transposed Vtg.
// No __syncthreads anywhere: 16 independent wave-streams per CU hide latency.
__global__ __launch_bounds__(256, 4) void attn_mfma(const bf16* __restrict__ qkv,
                                                    const bf16* __restrict__ vtg,
                                                    bf16* __restrict__ sa)
{
  __shared__ alignas(16) short Ps[4][16 * 72];    // per-wave [q][key], stride 72
  const int tid = threadIdx.x;
  const int bh = blockIdx.x;
  const int qt = 31 - blockIdx.y;                 // longest blocks dispatch first
  const size_t base = (size_t)bh * 393216;        // (bh*128) * 3072
  const int wave = tid >> 6;
  const int lane = tid & 63;
  const int l15 = lane & 15;
  const int l4 = lane >> 4;
  const unsigned short* qk = (const unsigned short*)qkv;
  const unsigned short* vtb = (const unsigned short*)vtg + (size_t)bh * 131072;  // 64*2048
  short* psw = &Ps[wave][0];

  // Q B-frag: B[n=q(l15)][k=d(l4*8+j)]
  const unsigned short* pq = qk + base + (size_t)(qt * 4 + wave) * 3072 + l15 * 192 + l4 * 8;
  short8 qf0 = *(const short8*)pq;
  short8 qf1 = *(const short8*)(pq + 32);

  f32x4 o[4] = {};                 // O^T: col=q(l15), row=d(16jn+4l4+r)
  float mloc = -__builtin_inff();  // per-lane = per-q-row
  float lsum = 0.f;

  for (int kt = 0; kt <= qt; ++kt) {
    // K A-frags: A[m=key(l15)][k=d]
    short8 kf0[4], kf1[4];
#pragma unroll
    for (int t = 0; t < 4; ++t) {
      const unsigned short* pk =
          qk + base + (size_t)(kt * 4 + t) * 3072 + l15 * 192 + 64 + l4 * 8;
      kf0[t] = *(const short8*)pk;
      kf1[t] = *(const short8*)(pk + 32);
    }

    // ---- S^T = K . Q^T : col=q(l15), row=key_local(16t+4l4+r)
    f32x4 sc[4];
#pragma unroll
    for (int t = 0; t < 4; ++t) {
      f32x4 c = {};
      c = __builtin_amdgcn_mfma_f32_16x16x32_bf16(kf0[t], qf0, c, 0, 0, 0);
      c = __builtin_amdgcn_mfma_f32_16x16x32_bf16(kf1[t], qf1, c, 0, 0, 0);
      sc[t] = c;
    }

    if (kt == qt) {                // wave-uniform diag branch
      const int qloc = wave * 16 + l15;
#pragma unroll
      for (int t = 0; t < 4; ++t)
#pragma unroll
        for (int r = 0; r < 4; ++r)
          if (16 * t + 4 * l4 + r > qloc) sc[t][r] = -__builtin_inff();
    }

    // V A-frags first half (keys kt*64 + l4*8, d = jn*16+l15): issue now,
    // latency hides under softmax (kf regs are dead here -> no pressure spike)
    short8 vf0[4];
#pragma unroll
    for (int jn = 0; jn < 4; ++jn)
      vf0[jn] = *(const short8*)(vtb + (size_t)(jn * 16 + l15) * 2048 + kt * 64 + l4 * 8);

    // ---- lane-local online softmax over this lane's 16 keys + cross-l4 reduce
    float mx = -__builtin_inff();
#pragma unroll
    for (int t = 0; t < 4; ++t)
#pragma unroll
      for (int r = 0; r < 4; ++r) mx = fmaxf(mx, sc[t][r]);
    mx = fmaxf(mx, __shfl_xor(mx, 16, 64));
    mx = fmaxf(mx, __shfl_xor(mx, 32, 64));
    const float m_new = fmaxf(mloc, mx);
    const float alpha = __builtin_amdgcn_exp2f(mloc - m_new);
    mloc = m_new;
    float s = 0.f;
    unsigned int pk2[4][2];
#pragma unroll
    for (int t = 0; t < 4; ++t) {
      float p0 = __builtin_amdgcn_exp2f(sc[t][0] - m_new);
      float p1 = __builtin_amdgcn_exp2f(sc[t][1] - m_new);
      float p2 = __builtin_amdgcn_exp2f(sc[t][2] - m_new);
      float p3 = __builtin_amdgcn_exp2f(sc[t][3] - m_new);
      s += (p0 + p1) + (p2 + p3);
      pk2[t][0] = pack2bf(p0, p1);
      pk2[t][1] = pack2bf(p2, p3);
    }
    s += __shfl_xor(s, 16, 64);
    s += __shfl_xor(s, 32, 64);
    lsum = lsum * alpha + s;
#pragma unroll
    for (int jn = 0; jn < 4; ++jn)
#pragma unroll
      for (int r = 0; r < 4; ++r) o[jn][r] *= alpha;

    // V A-frags second half (keys kt*64+32+l4*8): latency hides under P roundtrip
    short8 vf1[4];
#pragma unroll
    for (int jn = 0; jn < 4; ++jn)
      vf1[jn] = *(const short8*)(vtb + (size_t)(jn * 16 + l15) * 2048 + kt * 64 + 32 + l4 * 8);

    // ---- P -> LDS [q][key]: lane writes its 4 consecutive keys per tile (b64)
#pragma unroll
    for (int t = 0; t < 4; ++t) {
      uint2 w; w.x = pk2[t][0]; w.y = pk2[t][1];
      *(uint2*)(psw + l15 * 72 + 16 * t + 4 * l4) = w;
    }
    // B-frag read (same wave, program-ordered: no barrier needed)
    short8 pf0 = *(const short8*)(psw + l15 * 72 + l4 * 8);
    short8 pf1 = *(const short8*)(psw + l15 * 72 + 32 + l4 * 8);

    // ---- O^T += V^T . P^T : A[m=d][k=key] from Vtg, B[n=q][k=key] = P
#pragma unroll
    for (int jn = 0; jn < 4; ++jn)
      o[jn] = __builtin_amdgcn_mfma_f32_16x16x32_bf16(vf0[jn], pf0, o[jn], 0, 0, 0);
#pragma unroll
    for (int jn = 0; jn < 4; ++jn)
      o[jn] = __builtin_amdgcn_mfma_f32_16x16x32_bf16(vf1[jn], pf1, o[jn], 0, 0, 0);
  }

  // ---- epilogue: lane owns q row (qt*4+wave, inner l15); d = 16jn+4l4+r
  const float inv = 1.0f / lsum;
  unsigned short* so = (unsigned short*)sa + (size_t)(bh * 128 + qt * 4 + wave) * 1024;
#pragma unroll
  for (int jn = 0; jn < 4; ++jn) {
    uint2 w;
    w.x = pack2bf(o[jn][0] * inv, o[jn][1] * inv);
    w.y = pack2bf(o[jn][2] * inv, o[jn][3] * inv);
    *(uint2*)(so + l15 * 64 + jn * 16 + l4 * 4) = w;
  }
}

extern "C" void kernel_launch(void* const* d_in, const int* in_sizes, int n_in,
                              void* d_out, int out_size, void* d_ws, size_t ws_size,
                              hipStream_t stream)
{
  const void* x_raw    = d_in[0];  // [4,2048,1024]
  const void* Wqkv_raw = d_in[1];  // [1024,3072]
  const void* bqkv_raw = d_in[2];  // [3072]
  const void* Wout_raw = d_in[3];  // [1024,1024]
  const void* bout_raw = d_in[4];  // [1024]

  char* ws = (char*)d_ws;
  int*  flag   = (int*)ws;                                  //   256 B
  bf16* xb     = (bf16*)(ws + 256);                         //  16 MiB (8192*1024)
  bf16* wqkvT  = xb + (size_t)8192 * 1024;                  //   6 MiB (3072*1024, [N][K])
  bf16* bqkvb  = wqkvT + (size_t)3072 * 1024;               //   6 KiB
  bf16* woutT  = bqkvb + 4096;                              //   2 MiB (1024*1024, [N][K])
  bf16* boutb  = woutT + (size_t)1024 * 1024;               //   2 KiB
  bf16* qkv    = boutb + 4096;                              //  48 MiB (8192*3072)
  bf16* sa     = qkv + (size_t)8192 * 3072;                 //  16 MiB (8192*1024)
  bf16* vtg    = sa + (size_t)8192 * 1024;                  //  16 MiB (64*64*2048)

  detect_kernel<<<1, 64, 0, stream>>>((const unsigned int*)x_raw, flag);

  convert_kernel<<<(8192 * 1024 / 8 + 255) / 256, 256, 0, stream>>>(x_raw, xb, 8192 * 1024 / 8, flag);
  convert_bias_qkv<<<12, 256, 0, stream>>>(bqkv_raw, bqkvb, flag);
  convert_kernel<<<1, 256, 0, stream>>>(bout_raw, boutb, 1024 / 8, flag);
  transpose_bf16<<<dim3(3072 / 32, 1024 / 32), 256, 0, stream>>>(Wqkv_raw, wqkvT, 1024, 3072, flag, 1);
  transpose_bf16<<<dim3(1024 / 32, 1024 / 32), 256, 0, stream>>>(Wout_raw, woutT, 1024, 1024, flag, 0);

  // 1) qkv = x @ W_qkv + b_qkv   (M=8192, N=3072, K=1024); Q cols pre-scaled
  gemm_mfma<<<dim3(3072 / 128, 8192 / 128), 256, 0, stream>>>(
      xb, wqkvT, bqkvb, qkv, 8192, 3072, 1024, 0, flag);
  // 1b) V pre-transpose: Vtg[bh][d][key]
  transpose_v<<<dim3(64, 32), 256, 0, stream>>>(qkv, vtg);
  // 2) MFMA flash attention: barrier-free, one q-tile per block
  attn_mfma<<<dim3(64, 32), 256, 0, stream>>>(qkv, vtg, sa);
  // 3) out = sa @ W_out + b_out  (M=8192, N=1024, K=1024)
  gemm_mfma<<<dim3(1024 / 128, 8192 / 128), 256, 0, stream>>>(
      sa, woutT, boutb, d_out, 8192, 1024, 1024, 1, flag);
}

// Round 5
// 315.486 us; speedup vs baseline: 1.5870x; 1.4677x over previous
//
#include <hip/hip_runtime.h>
#include <hip/hip_bf16.h>

using bf16 = __hip_bfloat16;

typedef __attribute__((ext_vector_type(8))) short short8;   // 8 x bf16 (4 VGPRs)
typedef __attribute__((ext_vector_type(4))) float f32x4;    // MFMA C/D

// MaskedMSA: B=4, S=2048, E=1024, HIDDEN=1024, HEADS=16
// Reference reshape mixes seq/hidden: with t=16u+r (u<128, r<16):
//   q[b,h,t,e] = qkv[b, 128h+u, 192r +   0 + e]
//   k[b,h,t,e] = qkv[b, 128h+u, 192r +  64 + e]
//   v[b,h,t,e] = qkv[b, 128h+u, 192r + 128 + e]
// Output: sa[b,h,t,e] -> out row 128h+u, col 64r+e. Causal mask on permuted t.
// Q columns of W_qkv/b_qkv are pre-scaled by scale*log2(e): exp2-domain scores.
//
// R1-R4 lessons: the 1-wave 16x16 q-tile structure is a structural plateau
// (165/172/295/286/252 us under every perturbation). R5: QBLK=32 per wave,
// K/V staged cooperatively in frag-shaped LDS (1 global_load_lds16/thread),
// double-buffered, one barrier/iter, 4 waves share K/V, uniform paired chunks.

#define CEXP 0.03188127742677263f  // (2*1024)^-0.5 * log2(e)

__device__ __forceinline__ unsigned short f2bf(float v) {
  bf16 h = __float2bfloat16(v);
  return *(unsigned short*)&h;
}
__device__ __forceinline__ unsigned int pack2bf(float a, float b) {
  return (unsigned int)f2bf(a) | ((unsigned int)f2bf(b) << 16);
}

// async global->LDS, 16B per lane; LDS dest = wave-uniform base + lane*16.
__device__ __forceinline__ void gload_lds16(const void* g, void* lds) {
  __builtin_amdgcn_global_load_lds(
      (const __attribute__((address_space(1))) unsigned int*)(g),
      (__attribute__((address_space(3))) unsigned int*)(lds), 16, 0, 0);
}

// ---- dtype detect: flag=1 if fp32 I/O, flag=0 if bf16 I/O.
__global__ void detect_kernel(const unsigned int* __restrict__ x, int* __restrict__ flag) {
  unsigned int w = x[threadIdx.x];
  unsigned int e = (w >> 7) & 0xFF;
  bool inband = (e >= 96 && e <= 133);
  unsigned long long m = __ballot(inband);
  if (threadIdx.x == 0) flag[0] = (__popcll(m) >= 48) ? 0 : 1;
}

// ---- convert n8*8 elements to bf16 (copy if already bf16)
__global__ __launch_bounds__(256) void convert_kernel(
    const void* __restrict__ src, bf16* __restrict__ dst, int n8,
    const int* __restrict__ flag) {
  int i = blockIdx.x * 256 + threadIdx.x;
  if (i >= n8) return;
  uint4 outv;
  if (*flag) {
    const float4* s = (const float4*)src + (size_t)i * 2;
    float4 a = s[0], b = s[1];
    outv.x = pack2bf(a.x, a.y);
    outv.y = pack2bf(a.z, a.w);
    outv.z = pack2bf(b.x, b.y);
    outv.w = pack2bf(b.z, b.w);
  } else {
    outv = ((const uint4*)src)[i];
  }
  ((uint4*)dst)[i] = outv;
}

// ---- b_qkv convert with Q-column pre-scale (cols with (i%192)<64)
__global__ void convert_bias_qkv(const void* __restrict__ src, bf16* __restrict__ dst,
                                 const int* __restrict__ flag) {
  int i = blockIdx.x * 256 + threadIdx.x;
  if (i >= 3072) return;
  float v = (*flag) ? ((const float*)src)[i]
                    : __bfloat162float(((const bf16*)src)[i]);
  if ((i % 192) < 64) v *= CEXP;
  dst[i] = __float2bfloat16(v);
}

// ---- transpose src[R][C] -> dst[C][R] (bf16 out); qscale: scale rows n with
// (n%192)<64 by CEXP (W_qkv Q columns -> exp2 domain).
__global__ __launch_bounds__(256) void transpose_bf16(
    const void* __restrict__ src, bf16* __restrict__ dst, int R, int Cc,
    const int* __restrict__ flag, int qscale) {
  __shared__ float tile[32][33];
  const int c0 = blockIdx.x * 32, r0 = blockIdx.y * 32;
  const int tx = threadIdx.x & 31, ty = threadIdx.x >> 5;  // 32 x 8
  const bool f32 = (*flag != 0);
#pragma unroll
  for (int it = 0; it < 4; ++it) {
    int r = ty + it * 8;
    float v;
    if (f32) v = ((const float*)src)[(size_t)(r0 + r) * Cc + c0 + tx];
    else     v = __bfloat162float(((const bf16*)src)[(size_t)(r0 + r) * Cc + c0 + tx]);
    tile[r][tx] = v;
  }
  __syncthreads();
#pragma unroll
  for (int it = 0; it < 4; ++it) {
    int r = ty + it * 8;   // dst row n = c0 + r
    float vv = tile[tx][r];
    if (qscale && (((c0 + r) % 192) < 64)) vv *= CEXP;
    dst[(size_t)(c0 + r) * R + r0 + tx] = __float2bfloat16(vv);
  }
}

// ---- V pre-transpose: Vtg[bh][d][key] (d<64, key<2048) from permuted qkv.
__global__ __launch_bounds__(256) void transpose_v(const bf16* __restrict__ qkv,
                                                   bf16* __restrict__ vtg)
{
  __shared__ short tile[64][72];
  const int bh = blockIdx.x;
  const int k0 = blockIdx.y * 64;
  const unsigned short* qk = (const unsigned short*)qkv + (size_t)bh * 393216;
  const int key = threadIdx.x & 63;
  const int dv = threadIdx.x >> 6;      // 0..3 -> d-range dv*16
  const int gk = k0 + key;
  const unsigned short* src =
      qk + (size_t)(gk >> 4) * 3072 + (gk & 15) * 192 + 128 + dv * 16;
  *(short8*)&tile[key][dv * 16] = *(const short8*)src;
  *(short8*)&tile[key][dv * 16 + 8] = *(const short8*)(src + 8);
  __syncthreads();
  const int d = threadIdx.x & 63;
  const int kv = threadIdx.x >> 6;      // 0..3 -> key-range kv*16
  unsigned short* dst =
      (unsigned short*)vtg + ((size_t)bh * 64 + d) * 2048 + k0 + kv * 16;
  short8 a, b;
#pragma unroll
  for (int j = 0; j < 8; ++j) {
    a[j] = tile[kv * 16 + j][d];
    b[j] = tile[kv * 16 + 8 + j][d];
  }
  *(short8*)dst = a;
  *(short8*)(dst + 8) = b;
}

// ---------------- MFMA GEMM (m97 pattern): C[M,N] = A[M,K] @ BT[N,K]^T + bias
__global__ __launch_bounds__(256) void gemm_mfma(
    const bf16* __restrict__ A, const bf16* __restrict__ BT,
    const bf16* __restrict__ bias, void* __restrict__ C,
    int M, int N, int K, int store_mode, const int* __restrict__ flag)
{
  __shared__ alignas(16) unsigned short As[128 * 32];  // [m][k] contiguous
  __shared__ alignas(16) unsigned short Bs[128 * 32];  // [n][k] contiguous
  const bool store_f32 = store_mode && (*flag != 0);
  const int tid = threadIdx.x;
  const int wave = tid >> 6, lane = tid & 63;
  const int l15 = lane & 15, l4 = lane >> 4;
  const int m0 = blockIdx.y * 128, n0 = blockIdx.x * 128;
  const int wm = (wave & 1) * 64, wn = (wave >> 1) * 64;

  const int srow = wave * 32 + (lane >> 2);
  const int skv = (lane & 3) * 8;
  const bf16* ga = A + (size_t)(m0 + srow) * K + skv;
  const bf16* gb = BT + (size_t)(n0 + srow) * K + skv;
  unsigned short* la = As + (wave * 32) * 32;
  unsigned short* lb = Bs + (wave * 32) * 32;

  f32x4 acc[4][4] = {};

  for (int k0 = 0; k0 < K; k0 += 32) {
    __syncthreads();
    gload_lds16(ga, la);
    gload_lds16(ga + (size_t)16 * K, la + 16 * 32);
    gload_lds16(gb, lb);
    gload_lds16(gb + (size_t)16 * K, lb + 16 * 32);
    ga += 32; gb += 32;
    __syncthreads();

    short8 af[4], bfr[4];
#pragma unroll
    for (int i = 0; i < 4; ++i) {
      af[i]  = *(const short8*)(As + (wm + i * 16 + l15) * 32 + l4 * 8);
      bfr[i] = *(const short8*)(Bs + (wn + i * 16 + l15) * 32 + l4 * 8);
    }
#pragma unroll
    for (int i = 0; i < 4; ++i)
#pragma unroll
      for (int j = 0; j < 4; ++j)
        acc[i][j] = __builtin_amdgcn_mfma_f32_16x16x32_bf16(af[i], bfr[j], acc[i][j], 0, 0, 0);
  }

#pragma unroll
  for (int j = 0; j < 4; ++j) {
    const int n = n0 + wn + j * 16 + l15;
    const float bv = __bfloat162float(bias[n]);
#pragma unroll
    for (int i = 0; i < 4; ++i) {
#pragma unroll
      for (int r = 0; r < 4; ++r) {
        const int mrow = m0 + wm + i * 16 + l4 * 4 + r;
        const float v = acc[i][j][r] + bv;
        if (store_f32) ((float*)C)[(size_t)mrow * N + n] = v;
        else           ((bf16*)C)[(size_t)mrow * N + n] = __float2bfloat16(v);
      }
    }
  }
}

// ---------------- MFMA flash attention: 4 waves x QBLK=32, shared LDS K/V.
// grid (64 bh, 8 pair); block runs chunks {15-pr, pr} (128 q-rows each,
// uniform 34 iters total). Per iter (64 keys): K/V staged double-buffered in
// frag-shaped LDS ([chunk8][idx64][8 shorts]) via 1 global_load_lds16 per
// thread per tensor; S^T = mfma(K,Q) per q-subtile h; lane-local softmax
// (verified R0 math); P via per-wave LDS roundtrip; O^T = mfma(Vt,P).
// One barrier per iter; stage issued at iter top, flies under compute.
__global__ __launch_bounds__(256) void attn_mfma(const bf16* __restrict__ qkv,
                                                 const bf16* __restrict__ vtg,
                                                 bf16* __restrict__ sa)
{
  __shared__ alignas(16) short Ks[2][4096];   // [buf] [dchunk8][key64][8]
  __shared__ alignas(16) short Vs[2][4096];   // [buf] [kchunk8][d64][8]
  __shared__ alignas(16) short Ps[4][2304];   // per-wave [q32][key64 pad->72]
  const int tid = threadIdx.x;
  const int bh = blockIdx.x;
  const int pr = blockIdx.y;                  // 0..7
  const size_t base = (size_t)bh * 393216;    // (bh*128)*3072
  const int w = tid >> 6, lane = tid & 63;
  const int l15 = lane & 15, l4 = lane >> 4;
  const unsigned short* qk = (const unsigned short*)qkv;
  const unsigned short* vtb = (const unsigned short*)vtg + (size_t)bh * 131072;  // 64*2048
  short* psw = &Ps[w][0];

  // staging sources (lane part); kt adds 12288 (K: 4 rows) / 64 (V: keys)
  const unsigned short* ksrc0 = qk + base + (size_t)(lane >> 4) * 3072 + (lane & 15) * 192 + 64;
  const unsigned short* vsrc0 = vtb + (size_t)lane * 2048;

#pragma unroll 1
  for (int half = 0; half < 2; ++half) {
    const int qc = half ? pr : 15 - pr;       // long chunk first
    const int ktmax = 2 * qc + 1;

    // Q frags: B[n=q(16h+l15)][k=d(32kk+8l4+j)]; sa row u = qc*8+2w+h, r=l15
    short8 qf[2][2];
#pragma unroll
    for (int h = 0; h < 2; ++h) {
      const unsigned short* pq =
          qk + base + (size_t)(qc * 8 + 2 * w + h) * 3072 + l15 * 192 + l4 * 8;
      qf[h][0] = *(const short8*)pq;
      qf[h][1] = *(const short8*)(pq + 32);
    }

    f32x4 o[2][4] = {};                 // O^T: col=q(l15), row=d(16jn+4l4+r)
    float ml[2] = {-__builtin_inff(), -__builtin_inff()};
    float ls[2] = {0.f, 0.f};
    int cur = 0;

    // prologue: stage kt=0 into buf 0
#pragma unroll
    for (int rd = 0; rd < 2; ++rd) {
      const int dc = w + 4 * rd;
      gload_lds16(ksrc0 + dc * 8, &Ks[0][dc * 512]);
      gload_lds16(vsrc0 + dc * 8, &Vs[0][dc * 512]);
    }
    __syncthreads();

    for (int kt = 0; kt <= ktmax; ++kt) {
      // stage kt+1 into the other buffer (flies under this iter's compute)
      if (kt < ktmax) {
        const int nb = cur ^ 1;
#pragma unroll
        for (int rd = 0; rd < 2; ++rd) {
          const int dc = w + 4 * rd;
          gload_lds16(ksrc0 + (size_t)(kt + 1) * 12288 + dc * 8, &Ks[nb][dc * 512]);
          gload_lds16(vsrc0 + (kt + 1) * 64 + dc * 8, &Vs[nb][dc * 512]);
        }
      }

      // ---- S^T = K . Q^T per q-subtile h: col=q(l15), row=key(16t+4l4+r)
      f32x4 sc[2][4];
#pragma unroll
      for (int t = 0; t < 4; ++t) {
        const short8 kf0 = *(const short8*)&Ks[cur][(l4) * 512 + (16 * t + l15) * 8];
        const short8 kf1 = *(const short8*)&Ks[cur][(4 + l4) * 512 + (16 * t + l15) * 8];
#pragma unroll
        for (int h = 0; h < 2; ++h) {
          f32x4 c = {};
          c = __builtin_amdgcn_mfma_f32_16x16x32_bf16(kf0, qf[h][0], c, 0, 0, 0);
          c = __builtin_amdgcn_mfma_f32_16x16x32_bf16(kf1, qf[h][1], c, 0, 0, 0);
          sc[h][t] = c;
        }
      }

      // ---- causal mask on the (at most 2) diagonal iterations
      if (kt >= 2 * qc) {
        const int kb = 64 * (kt - 2 * qc);
#pragma unroll
        for (int h = 0; h < 2; ++h) {
          const int thr = 32 * w + 16 * h + l15;
#pragma unroll
          for (int t = 0; t < 4; ++t)
#pragma unroll
            for (int r = 0; r < 4; ++r)
              if (kb + 16 * t + 4 * l4 + r > thr) sc[h][t][r] = -__builtin_inff();
        }
      }

      // ---- lane-local online softmax per h (16 keys/lane + cross-l4 reduce)
      unsigned int pk2[2][4][2];
#pragma unroll
      for (int h = 0; h < 2; ++h) {
        float mx = -__builtin_inff();
#pragma unroll
        for (int t = 0; t < 4; ++t)
#pragma unroll
          for (int r = 0; r < 4; ++r) mx = fmaxf(mx, sc[h][t][r]);
        mx = fmaxf(mx, __shfl_xor(mx, 16, 64));
        mx = fmaxf(mx, __shfl_xor(mx, 32, 64));
        const float m_new = fmaxf(ml[h], mx);
        const float alpha = __builtin_amdgcn_exp2f(ml[h] - m_new);
        ml[h] = m_new;
        float s = 0.f;
#pragma unroll
        for (int t = 0; t < 4; ++t) {
          float p0 = __builtin_amdgcn_exp2f(sc[h][t][0] - m_new);
          float p1 = __builtin_amdgcn_exp2f(sc[h][t][1] - m_new);
          float p2 = __builtin_amdgcn_exp2f(sc[h][t][2] - m_new);
          float p3 = __builtin_amdgcn_exp2f(sc[h][t][3] - m_new);
          s += (p0 + p1) + (p2 + p3);
          pk2[h][t][0] = pack2bf(p0, p1);
          pk2[h][t][1] = pack2bf(p2, p3);
        }
        s += __shfl_xor(s, 16, 64);
        s += __shfl_xor(s, 32, 64);
        ls[h] = ls[h] * alpha + s;
#pragma unroll
        for (int jn = 0; jn < 4; ++jn)
#pragma unroll
          for (int r = 0; r < 4; ++r) o[h][jn][r] *= alpha;
      }

      // ---- P -> per-wave LDS [q][key] (rows disjoint per h), then B-frags
#pragma unroll
      for (int h = 0; h < 2; ++h)
#pragma unroll
        for (int t = 0; t < 4; ++t) {
          uint2 wv; wv.x = pk2[h][t][0]; wv.y = pk2[h][t][1];
          *(uint2*)(psw + (16 * h + l15) * 72 + 16 * t + 4 * l4) = wv;
        }
      short8 pf[2][2];
#pragma unroll
      for (int h = 0; h < 2; ++h)
#pragma unroll
        for (int ks = 0; ks < 2; ++ks)
          pf[h][ks] = *(const short8*)(psw + (16 * h + l15) * 72 + 32 * ks + 8 * l4);

      // ---- O^T += V^T . P^T : A[m=d(16jn+l15)][k=key(32ks+8l4+j)] from Vs
#pragma unroll
      for (int jn = 0; jn < 4; ++jn)
#pragma unroll
        for (int ks = 0; ks < 2; ++ks) {
          const short8 vf =
              *(const short8*)&Vs[cur][(4 * ks + l4) * 512 + (16 * jn + l15) * 8];
#pragma unroll
          for (int h = 0; h < 2; ++h)
            o[h][jn] = __builtin_amdgcn_mfma_f32_16x16x32_bf16(vf, pf[h][ks], o[h][jn], 0, 0, 0);
        }

      __syncthreads();   // staged kt+1 ready (vmcnt drain); buf reads done
      cur ^= 1;
    }

    // ---- epilogue: q row u = qc*8+2w+h, r=l15; col = 64*l15 + 16jn+4l4+r
#pragma unroll
    for (int h = 0; h < 2; ++h) {
      const float inv = 1.0f / ls[h];
      unsigned short* so =
          (unsigned short*)sa + (size_t)(bh * 128 + qc * 8 + 2 * w + h) * 1024;
#pragma unroll
      for (int jn = 0; jn < 4; ++jn) {
        uint2 wv;
        wv.x = pack2bf(o[h][jn][0] * inv, o[h][jn][1] * inv);
        wv.y = pack2bf(o[h][jn][2] * inv, o[h][jn][3] * inv);
        *(uint2*)(so + l15 * 64 + jn * 16 + l4 * 4) = wv;
      }
    }
  }
}

extern "C" void kernel_launch(void* const* d_in, const int* in_sizes, int n_in,
                              void* d_out, int out_size, void* d_ws, size_t ws_size,
                              hipStream_t stream)
{
  const void* x_raw    = d_in[0];  // [4,2048,1024]
  const void* Wqkv_raw = d_in[1];  // [1024,3072]
  const void* bqkv_raw = d_in[2];  // [3072]
  const void* Wout_raw = d_in[3];  // [1024,1024]
  const void* bout_raw = d_in[4];  // [1024]

  char* ws = (char*)d_ws;
  int*  flag   = (int*)ws;                                  //   256 B
  bf16* xb     = (bf16*)(ws + 256);                         //  16 MiB (8192*1024)
  bf16* wqkvT  = xb + (size_t)8192 * 1024;                  //   6 MiB (3072*1024, [N][K])
  bf16* bqkvb  = wqkvT + (size_t)3072 * 1024;               //   6 KiB
  bf16* woutT  = bqkvb + 4096;                              //   2 MiB (1024*1024, [N][K])
  bf16* boutb  = woutT + (size_t)1024 * 1024;               //   2 KiB
  bf16* qkv    = boutb + 4096;                              //  48 MiB (8192*3072)
  bf16* sa     = qkv + (size_t)8192 * 3072;                 //  16 MiB (8192*1024)
  bf16* vtg    = sa + (size_t)8192 * 1024;                  //  16 MiB (64*64*2048)

  detect_kernel<<<1, 64, 0, stream>>>((const unsigned int*)x_raw, flag);

  convert_kernel<<<(8192 * 1024 / 8 + 255) / 256, 256, 0, stream>>>(x_raw, xb, 8192 * 1024 / 8, flag);
  convert_bias_qkv<<<12, 256, 0, stream>>>(bqkv_raw, bqkvb, flag);
  convert_kernel<<<1, 256, 0, stream>>>(bout_raw, boutb, 1024 / 8, flag);
  transpose_bf16<<<dim3(3072 / 32, 1024 / 32), 256, 0, stream>>>(Wqkv_raw, wqkvT, 1024, 3072, flag, 1);
  transpose_bf16<<<dim3(1024 / 32, 1024 / 32), 256, 0, stream>>>(Wout_raw, woutT, 1024, 1024, flag, 0);

  // 1) qkv = x @ W_qkv + b_qkv   (M=8192, N=3072, K=1024); Q cols pre-scaled
  gemm_mfma<<<dim3(3072 / 128, 8192 / 128), 256, 0, stream>>>(
      xb, wqkvT, bqkvb, qkv, 8192, 3072, 1024, 0, flag);
  // 1b) V pre-transpose: Vtg[bh][d][key]
  transpose_v<<<dim3(64, 32), 256, 0, stream>>>(qkv, vtg);
  // 2) MFMA flash attention: 4 waves x QBLK=32, LDS-shared K/V, paired chunks
  attn_mfma<<<dim3(64, 8), 256, 0, stream>>>(qkv, vtg, sa);
  // 3) out = sa @ W_out + b_out  (M=8192, N=1024, K=1024)
  gemm_mfma<<<dim3(1024 / 128, 8192 / 128), 256, 0, stream>>>(
      sa, woutT, boutb, d_out, 8192, 1024, 1024, 1, flag);
}

// Round 8
// 302.443 us; speedup vs baseline: 1.6554x; 1.0431x over previous
//
#include <hip/hip_runtime.h>
#include <hip/hip_bf16.h>

using bf16 = __hip_bfloat16;

typedef __attribute__((ext_vector_type(8))) short short8;   // 8 x bf16 (4 VGPRs)
typedef __attribute__((ext_vector_type(4))) float f32x4;    // MFMA C/D

// MaskedMSA: B=4, S=2048, E=1024, HIDDEN=1024, HEADS=16
// Reference reshape mixes seq/hidden: with t=16u+r (u<128, r<16):
//   q[b,h,t,e] = qkv[b, 128h+u, 192r +   0 + e]
//   k[b,h,t,e] = qkv[b, 128h+u, 192r +  64 + e]
//   v[b,h,t,e] = qkv[b, 128h+u, 192r + 128 + e]
// Output: sa[b,h,t,e] -> out row 128h+u, col 64r+e. Causal mask on permuted t.
// Q columns of W_qkv/b_qkv are pre-scaled by scale*log2(e): exp2-domain scores.
//
// R1-R4 lessons: the 1-wave 16x16 q-tile structure is a structural plateau.
// R5 (WIN, 165->96us): QBLK=32 per wave, K/V staged cooperatively in
// frag-shaped LDS, double-buffered, one barrier/iter, 4 waves share K/V.
// R6: occupancy was grid-capped (paired grid 512 blocks = 2/CU; LDS allows 3).
// Un-pair chunks: grid 64x16, one chunk per block, longest-first.
// (R6/R7 benches were broker-level infra failures -- container acquisition
// died before kernel upload; resubmitting unchanged, third attempt.)

#define CEXP 0.03188127742677263f  // (2*1024)^-0.5 * log2(e)

__device__ __forceinline__ unsigned short f2bf(float v) {
  bf16 h = __float2bfloat16(v);
  return *(unsigned short*)&h;
}
__device__ __forceinline__ unsigned int pack2bf(float a, float b) {
  return (unsigned int)f2bf(a) | ((unsigned int)f2bf(b) << 16);
}

// async global->LDS, 16B per lane; LDS dest = wave-uniform base + lane*16.
__device__ __forceinline__ void gload_lds16(const void* g, void* lds) {
  __builtin_amdgcn_global_load_lds(
      (const __attribute__((address_space(1))) unsigned int*)(g),
      (__attribute__((address_space(3))) unsigned int*)(lds), 16, 0, 0);
}

// ---- dtype detect: flag=1 if fp32 I/O, flag=0 if bf16 I/O.
__global__ void detect_kernel(const unsigned int* __restrict__ x, int* __restrict__ flag) {
  unsigned int w = x[threadIdx.x];
  unsigned int e = (w >> 7) & 0xFF;
  bool inband = (e >= 96 && e <= 133);
  unsigned long long m = __ballot(inband);
  if (threadIdx.x == 0) flag[0] = (__popcll(m) >= 48) ? 0 : 1;
}

// ---- convert n8*8 elements to bf16 (copy if already bf16)
__global__ __launch_bounds__(256) void convert_kernel(
    const void* __restrict__ src, bf16* __restrict__ dst, int n8,
    const int* __restrict__ flag) {
  int i = blockIdx.x * 256 + threadIdx.x;
  if (i >= n8) return;
  uint4 outv;
  if (*flag) {
    const float4* s = (const float4*)src + (size_t)i * 2;
    float4 a = s[0], b = s[1];
    outv.x = pack2bf(a.x, a.y);
    outv.y = pack2bf(a.z, a.w);
    outv.z = pack2bf(b.x, b.y);
    outv.w = pack2bf(b.z, b.w);
  } else {
    outv = ((const uint4*)src)[i];
  }
  ((uint4*)dst)[i] = outv;
}

// ---- b_qkv convert with Q-column pre-scale (cols with (i%192)<64)
__global__ void convert_bias_qkv(const void* __restrict__ src, bf16* __restrict__ dst,
                                 const int* __restrict__ flag) {
  int i = blockIdx.x * 256 + threadIdx.x;
  if (i >= 3072) return;
  float v = (*flag) ? ((const float*)src)[i]
                    : __bfloat162float(((const bf16*)src)[i]);
  if ((i % 192) < 64) v *= CEXP;
  dst[i] = __float2bfloat16(v);
}

// ---- transpose src[R][C] -> dst[C][R] (bf16 out); qscale: scale rows n with
// (n%192)<64 by CEXP (W_qkv Q columns -> exp2 domain).
__global__ __launch_bounds__(256) void transpose_bf16(
    const void* __restrict__ src, bf16* __restrict__ dst, int R, int Cc,
    const int* __restrict__ flag, int qscale) {
  __shared__ float tile[32][33];
  const int c0 = blockIdx.x * 32, r0 = blockIdx.y * 32;
  const int tx = threadIdx.x & 31, ty = threadIdx.x >> 5;  // 32 x 8
  const bool f32 = (*flag != 0);
#pragma unroll
  for (int it = 0; it < 4; ++it) {
    int r = ty + it * 8;
    float v;
    if (f32) v = ((const float*)src)[(size_t)(r0 + r) * Cc + c0 + tx];
    else     v = __bfloat162float(((const bf16*)src)[(size_t)(r0 + r) * Cc + c0 + tx]);
    tile[r][tx] = v;
  }
  __syncthreads();
#pragma unroll
  for (int it = 0; it < 4; ++it) {
    int r = ty + it * 8;   // dst row n = c0 + r
    float vv = tile[tx][r];
    if (qscale && (((c0 + r) % 192) < 64)) vv *= CEXP;
    dst[(size_t)(c0 + r) * R + r0 + tx] = __float2bfloat16(vv);
  }
}

// ---- V pre-transpose: Vtg[bh][d][key] (d<64, key<2048) from permuted qkv.
__global__ __launch_bounds__(256) void transpose_v(const bf16* __restrict__ qkv,
                                                   bf16* __restrict__ vtg)
{
  __shared__ short tile[64][72];
  const int bh = blockIdx.x;
  const int k0 = blockIdx.y * 64;
  const unsigned short* qk = (const unsigned short*)qkv + (size_t)bh * 393216;
  const int key = threadIdx.x & 63;
  const int dv = threadIdx.x >> 6;      // 0..3 -> d-range dv*16
  const int gk = k0 + key;
  const unsigned short* src =
      qk + (size_t)(gk >> 4) * 3072 + (gk & 15) * 192 + 128 + dv * 16;
  *(short8*)&tile[key][dv * 16] = *(const short8*)src;
  *(short8*)&tile[key][dv * 16 + 8] = *(const short8*)(src + 8);
  __syncthreads();
  const int d = threadIdx.x & 63;
  const int kv = threadIdx.x >> 6;      // 0..3 -> key-range kv*16
  unsigned short* dst =
      (unsigned short*)vtg + ((size_t)bh * 64 + d) * 2048 + k0 + kv * 16;
  short8 a, b;
#pragma unroll
  for (int j = 0; j < 8; ++j) {
    a[j] = tile[kv * 16 + j][d];
    b[j] = tile[kv * 16 + 8 + j][d];
  }
  *(short8*)dst = a;
  *(short8*)(dst + 8) = b;
}

// ---------------- MFMA GEMM (m97 pattern): C[M,N] = A[M,K] @ BT[N,K]^T + bias
__global__ __launch_bounds__(256) void gemm_mfma(
    const bf16* __restrict__ A, const bf16* __restrict__ BT,
    const bf16* __restrict__ bias, void* __restrict__ C,
    int M, int N, int K, int store_mode, const int* __restrict__ flag)
{
  __shared__ alignas(16) unsigned short As[128 * 32];  // [m][k] contiguous
  __shared__ alignas(16) unsigned short Bs[128 * 32];  // [n][k] contiguous
  const bool store_f32 = store_mode && (*flag != 0);
  const int tid = threadIdx.x;
  const int wave = tid >> 6, lane = tid & 63;
  const int l15 = lane & 15, l4 = lane >> 4;
  const int m0 = blockIdx.y * 128, n0 = blockIdx.x * 128;
  const int wm = (wave & 1) * 64, wn = (wave >> 1) * 64;

  const int srow = wave * 32 + (lane >> 2);
  const int skv = (lane & 3) * 8;
  const bf16* ga = A + (size_t)(m0 + srow) * K + skv;
  const bf16* gb = BT + (size_t)(n0 + srow) * K + skv;
  unsigned short* la = As + (wave * 32) * 32;
  unsigned short* lb = Bs + (wave * 32) * 32;

  f32x4 acc[4][4] = {};

  for (int k0 = 0; k0 < K; k0 += 32) {
    __syncthreads();
    gload_lds16(ga, la);
    gload_lds16(ga + (size_t)16 * K, la + 16 * 32);
    gload_lds16(gb, lb);
    gload_lds16(gb + (size_t)16 * K, lb + 16 * 32);
    ga += 32; gb += 32;
    __syncthreads();

    short8 af[4], bfr[4];
#pragma unroll
    for (int i = 0; i < 4; ++i) {
      af[i]  = *(const short8*)(As + (wm + i * 16 + l15) * 32 + l4 * 8);
      bfr[i] = *(const short8*)(Bs + (wn + i * 16 + l15) * 32 + l4 * 8);
    }
#pragma unroll
    for (int i = 0; i < 4; ++i)
#pragma unroll
      for (int j = 0; j < 4; ++j)
        acc[i][j] = __builtin_amdgcn_mfma_f32_16x16x32_bf16(af[i], bfr[j], acc[i][j], 0, 0, 0);
  }

#pragma unroll
  for (int j = 0; j < 4; ++j) {
    const int n = n0 + wn + j * 16 + l15;
    const float bv = __bfloat162float(bias[n]);
#pragma unroll
    for (int i = 0; i < 4; ++i) {
#pragma unroll
      for (int r = 0; r < 4; ++r) {
        const int mrow = m0 + wm + i * 16 + l4 * 4 + r;
        const float v = acc[i][j][r] + bv;
        if (store_f32) ((float*)C)[(size_t)mrow * N + n] = v;
        else           ((bf16*)C)[(size_t)mrow * N + n] = __float2bfloat16(v);
      }
    }
  }
}

// ---------------- MFMA flash attention: 4 waves x QBLK=32, shared LDS K/V.
// grid (64 bh, 16 y); block owns chunk qc = 15-y (32 q-rows/wave, 128/block;
// longest chunks dispatch first; iters = 2qc+2). Per iter (64 keys): K/V
// staged double-buffered in frag-shaped LDS ([chunk8][idx64][8 shorts]) via
// 1 global_load_lds16 per thread per tensor; S^T = mfma(K,Q) per q-subtile h;
// lane-local softmax; P via per-wave LDS roundtrip; O^T = mfma(Vt,P).
// One barrier per iter. LDS 51.2KB -> 3 blocks/CU (grid now supplies 4).
__global__ __launch_bounds__(256) void attn_mfma(const bf16* __restrict__ qkv,
                                                 const bf16* __restrict__ vtg,
                                                 bf16* __restrict__ sa)
{
  __shared__ alignas(16) short Ks[2][4096];   // [buf] [dchunk8][key64][8]
  __shared__ alignas(16) short Vs[2][4096];   // [buf] [kchunk8][d64][8]
  __shared__ alignas(16) short Ps[4][2304];   // per-wave [q32][key64 pad->72]
  const int tid = threadIdx.x;
  const int bh = blockIdx.x;
  const int qc = 15 - blockIdx.y;             // longest chunks first
  const size_t base = (size_t)bh * 393216;    // (bh*128)*3072
  const int w = tid >> 6, lane = tid & 63;
  const int l15 = lane & 15, l4 = lane >> 4;
  const unsigned short* qk = (const unsigned short*)qkv;
  const unsigned short* vtb = (const unsigned short*)vtg + (size_t)bh * 131072;  // 64*2048
  short* psw = &Ps[w][0];

  // staging sources (lane part); kt adds 12288 (K: 4 rows) / 64 (V: keys)
  const unsigned short* ksrc0 = qk + base + (size_t)(lane >> 4) * 3072 + (lane & 15) * 192 + 64;
  const unsigned short* vsrc0 = vtb + (size_t)lane * 2048;

  const int ktmax = 2 * qc + 1;

  // Q frags: B[n=q(16h+l15)][k=d(32kk+8l4+j)]; sa row u = qc*8+2w+h, r=l15
  short8 qf[2][2];
#pragma unroll
  for (int h = 0; h < 2; ++h) {
    const unsigned short* pq =
        qk + base + (size_t)(qc * 8 + 2 * w + h) * 3072 + l15 * 192 + l4 * 8;
    qf[h][0] = *(const short8*)pq;
    qf[h][1] = *(const short8*)(pq + 32);
  }

  f32x4 o[2][4] = {};                 // O^T: col=q(l15), row=d(16jn+4l4+r)
  float ml[2] = {-__builtin_inff(), -__builtin_inff()};
  float ls[2] = {0.f, 0.f};
  int cur = 0;

  // prologue: stage kt=0 into buf 0
#pragma unroll
  for (int rd = 0; rd < 2; ++rd) {
    const int dc = w + 4 * rd;
    gload_lds16(ksrc0 + dc * 8, &Ks[0][dc * 512]);
    gload_lds16(vsrc0 + dc * 8, &Vs[0][dc * 512]);
  }
  __syncthreads();

  for (int kt = 0; kt <= ktmax; ++kt) {
    // stage kt+1 into the other buffer (flies under this iter's compute)
    if (kt < ktmax) {
      const int nb = cur ^ 1;
#pragma unroll
      for (int rd = 0; rd < 2; ++rd) {
        const int dc = w + 4 * rd;
        gload_lds16(ksrc0 + (size_t)(kt + 1) * 12288 + dc * 8, &Ks[nb][dc * 512]);
        gload_lds16(vsrc0 + (kt + 1) * 64 + dc * 8, &Vs[nb][dc * 512]);
      }
    }

    // ---- S^T = K . Q^T per q-subtile h: col=q(l15), row=key(16t+4l4+r)
    f32x4 sc[2][4];
#pragma unroll
    for (int t = 0; t < 4; ++t) {
      const short8 kf0 = *(const short8*)&Ks[cur][(l4) * 512 + (16 * t + l15) * 8];
      const short8 kf1 = *(const short8*)&Ks[cur][(4 + l4) * 512 + (16 * t + l15) * 8];
#pragma unroll
      for (int h = 0; h < 2; ++h) {
        f32x4 c = {};
        c = __builtin_amdgcn_mfma_f32_16x16x32_bf16(kf0, qf[h][0], c, 0, 0, 0);
        c = __builtin_amdgcn_mfma_f32_16x16x32_bf16(kf1, qf[h][1], c, 0, 0, 0);
        sc[h][t] = c;
      }
    }

    // ---- causal mask on the (at most 2) diagonal iterations
    if (kt >= 2 * qc) {
      const int kb = 64 * (kt - 2 * qc);
#pragma unroll
      for (int h = 0; h < 2; ++h) {
        const int thr = 32 * w + 16 * h + l15;
#pragma unroll
        for (int t = 0; t < 4; ++t)
#pragma unroll
          for (int r = 0; r < 4; ++r)
            if (kb + 16 * t + 4 * l4 + r > thr) sc[h][t][r] = -__builtin_inff();
      }
    }

    // ---- lane-local online softmax per h (16 keys/lane + cross-l4 reduce)
    unsigned int pk2[2][4][2];
#pragma unroll
    for (int h = 0; h < 2; ++h) {
      float mx = -__builtin_inff();
#pragma unroll
      for (int t = 0; t < 4; ++t)
#pragma unroll
        for (int r = 0; r < 4; ++r) mx = fmaxf(mx, sc[h][t][r]);
      mx = fmaxf(mx, __shfl_xor(mx, 16, 64));
      mx = fmaxf(mx, __shfl_xor(mx, 32, 64));
      const float m_new = fmaxf(ml[h], mx);
      const float alpha = __builtin_amdgcn_exp2f(ml[h] - m_new);
      ml[h] = m_new;
      float s = 0.f;
#pragma unroll
      for (int t = 0; t < 4; ++t) {
        float p0 = __builtin_amdgcn_exp2f(sc[h][t][0] - m_new);
        float p1 = __builtin_amdgcn_exp2f(sc[h][t][1] - m_new);
        float p2 = __builtin_amdgcn_exp2f(sc[h][t][2] - m_new);
        float p3 = __builtin_amdgcn_exp2f(sc[h][t][3] - m_new);
        s += (p0 + p1) + (p2 + p3);
        pk2[h][t][0] = pack2bf(p0, p1);
        pk2[h][t][1] = pack2bf(p2, p3);
      }
      s += __shfl_xor(s, 16, 64);
      s += __shfl_xor(s, 32, 64);
      ls[h] = ls[h] * alpha + s;
#pragma unroll
      for (int jn = 0; jn < 4; ++jn)
#pragma unroll
        for (int r = 0; r < 4; ++r) o[h][jn][r] *= alpha;
    }

    // ---- P -> per-wave LDS [q][key] (rows disjoint per h), then B-frags
#pragma unroll
    for (int h = 0; h < 2; ++h)
#pragma unroll
      for (int t = 0; t < 4; ++t) {
        uint2 wv; wv.x = pk2[h][t][0]; wv.y = pk2[h][t][1];
        *(uint2*)(psw + (16 * h + l15) * 72 + 16 * t + 4 * l4) = wv;
      }
    short8 pf[2][2];
#pragma unroll
    for (int h = 0; h < 2; ++h)
#pragma unroll
      for (int ks = 0; ks < 2; ++ks)
        pf[h][ks] = *(const short8*)(psw + (16 * h + l15) * 72 + 32 * ks + 8 * l4);

    // ---- O^T += V^T . P^T : A[m=d(16jn+l15)][k=key(32ks+8l4+j)] from Vs
#pragma unroll
    for (int jn = 0; jn < 4; ++jn)
#pragma unroll
      for (int ks = 0; ks < 2; ++ks) {
        const short8 vf =
            *(const short8*)&Vs[cur][(4 * ks + l4) * 512 + (16 * jn + l15) * 8];
#pragma unroll
        for (int h = 0; h < 2; ++h)
          o[h][jn] = __builtin_amdgcn_mfma_f32_16x16x32_bf16(vf, pf[h][ks], o[h][jn], 0, 0, 0);
      }

    __syncthreads();   // staged kt+1 ready (vmcnt drain); buf reads done
    cur ^= 1;
  }

  // ---- epilogue: q row u = qc*8+2w+h, r=l15; col = 64*l15 + 16jn+4l4+r
#pragma unroll
  for (int h = 0; h < 2; ++h) {
    const float inv = 1.0f / ls[h];
    unsigned short* so =
        (unsigned short*)sa + (size_t)(bh * 128 + qc * 8 + 2 * w + h) * 1024;
#pragma unroll
    for (int jn = 0; jn < 4; ++jn) {
      uint2 wv;
      wv.x = pack2bf(o[h][jn][0] * inv, o[h][jn][1] * inv);
      wv.y = pack2bf(o[h][jn][2] * inv, o[h][jn][3] * inv);
      *(uint2*)(so + l15 * 64 + jn * 16 + l4 * 4) = wv;
    }
  }
}

extern "C" void kernel_launch(void* const* d_in, const int* in_sizes, int n_in,
                              void* d_out, int out_size, void* d_ws, size_t ws_size,
                              hipStream_t stream)
{
  const void* x_raw    = d_in[0];  // [4,2048,1024]
  const void* Wqkv_raw = d_in[1];  // [1024,3072]
  const void* bqkv_raw = d_in[2];  // [3072]
  const void* Wout_raw = d_in[3];  // [1024,1024]
  const void* bout_raw = d_in[4];  // [1024]

  char* ws = (char*)d_ws;
  int*  flag   = (int*)ws;                                  //   256 B
  bf16* xb     = (bf16*)(ws + 256);                         //  16 MiB (8192*1024)
  bf16* wqkvT  = xb + (size_t)8192 * 1024;                  //   6 MiB (3072*1024, [N][K])
  bf16* bqkvb  = wqkvT + (size_t)3072 * 1024;               //   6 KiB
  bf16* woutT  = bqkvb + 4096;                              //   2 MiB (1024*1024, [N][K])
  bf16* boutb  = woutT + (size_t)1024 * 1024;               //   2 KiB
  bf16* qkv    = boutb + 4096;                              //  48 MiB (8192*3072)
  bf16* sa     = qkv + (size_t)8192 * 3072;                 //  16 MiB (8192*1024)
  bf16* vtg    = sa + (size_t)8192 * 1024;                  //  16 MiB (64*64*2048)

  detect_kernel<<<1, 64, 0, stream>>>((const unsigned int*)x_raw, flag);

  convert_kernel<<<(8192 * 1024 / 8 + 255) / 256, 256, 0, stream>>>(x_raw, xb, 8192 * 1024 / 8, flag);
  convert_bias_qkv<<<12, 256, 0, stream>>>(bqkv_raw, bqkvb, flag);
  convert_kernel<<<1, 256, 0, stream>>>(bout_raw, boutb, 1024 / 8, flag);
  transpose_bf16<<<dim3(3072 / 32, 1024 / 32), 256, 0, stream>>>(Wqkv_raw, wqkvT, 1024, 3072, flag, 1);
  transpose_bf16<<<dim3(1024 / 32, 1024 / 32), 256, 0, stream>>>(Wout_raw, woutT, 1024, 1024, flag, 0);

  // 1) qkv = x @ W_qkv + b_qkv   (M=8192, N=3072, K=1024); Q cols pre-scaled
  gemm_mfma<<<dim3(3072 / 128, 8192 / 128), 256, 0, stream>>>(
      xb, wqkvT, bqkvb, qkv, 8192, 3072, 1024, 0, flag);
  // 1b) V pre-transpose: Vtg[bh][d][key]
  transpose_v<<<dim3(64, 32), 256, 0, stream>>>(qkv, vtg);
  // 2) MFMA flash attention: one chunk per block (grid 64x16), 3 blocks/CU
  attn_mfma<<<dim3(64, 16), 256, 0, stream>>>(qkv, vtg, sa);
  // 3) out = sa @ W_out + b_out  (M=8192, N=1024, K=1024)
  gemm_mfma<<<dim3(1024 / 128, 8192 / 128), 256, 0, stream>>>(
      sa, woutT, boutb, d_out, 8192, 1024, 1024, 1, flag);
}

// Round 9
// 302.117 us; speedup vs baseline: 1.6572x; 1.0011x over previous
//
#include <hip/hip_runtime.h>
#include <hip/hip_bf16.h>

using bf16 = __hip_bfloat16;

typedef __attribute__((ext_vector_type(8))) short short8;   // 8 x bf16 (4 VGPRs)
typedef __attribute__((ext_vector_type(4))) float f32x4;    // MFMA C/D

// MaskedMSA: B=4, S=2048, E=1024, HIDDEN=1024, HEADS=16
// Reference reshape mixes seq/hidden: with t=16u+r (u<128, r<16):
//   q[b,h,t,e] = qkv[b, 128h+u, 192r +   0 + e]
//   k[b,h,t,e] = qkv[b, 128h+u, 192r +  64 + e]
//   v[b,h,t,e] = qkv[b, 128h+u, 192r + 128 + e]
// Output: sa[b,h,t,e] -> out row 128h+u, col 64r+e. Causal mask on permuted t.
// Q columns of W_qkv/b_qkv are pre-scaled by scale*log2(e): exp2-domain scores.
//
// R1-R4: 1-wave 16x16 q-tile structure = structural plateau (~165us floor).
// R5 (WIN 165->96us): QBLK=32/wave, K/V coop-staged frag-shaped LDS, dbuf,
// one barrier/iter. R8 (small win 96->89us): un-paired chunks; occupancy
// stuck ~20% (2 blocks/CU) despite grid 4/CU -> 51.2KB LDS is the residency
// cap (effective pool ~128KB). R9: (a) halve Ps (sequential h roundtrip) ->
// LDS 41984B, 3 blocks/CU; (b) T13 defer-max (skip alpha/rescale when
// __all(mx <= ml+8)) -> ~19% VALU cut per iter.

#define CEXP 0.03188127742677263f  // (2*1024)^-0.5 * log2(e)

__device__ __forceinline__ unsigned short f2bf(float v) {
  bf16 h = __float2bfloat16(v);
  return *(unsigned short*)&h;
}
__device__ __forceinline__ unsigned int pack2bf(float a, float b) {
  return (unsigned int)f2bf(a) | ((unsigned int)f2bf(b) << 16);
}

// async global->LDS, 16B per lane; LDS dest = wave-uniform base + lane*16.
__device__ __forceinline__ void gload_lds16(const void* g, void* lds) {
  __builtin_amdgcn_global_load_lds(
      (const __attribute__((address_space(1))) unsigned int*)(g),
      (__attribute__((address_space(3))) unsigned int*)(lds), 16, 0, 0);
}

// ---- dtype detect: flag=1 if fp32 I/O, flag=0 if bf16 I/O.
__global__ void detect_kernel(const unsigned int* __restrict__ x, int* __restrict__ flag) {
  unsigned int w = x[threadIdx.x];
  unsigned int e = (w >> 7) & 0xFF;
  bool inband = (e >= 96 && e <= 133);
  unsigned long long m = __ballot(inband);
  if (threadIdx.x == 0) flag[0] = (__popcll(m) >= 48) ? 0 : 1;
}

// ---- convert n8*8 elements to bf16 (copy if already bf16)
__global__ __launch_bounds__(256) void convert_kernel(
    const void* __restrict__ src, bf16* __restrict__ dst, int n8,
    const int* __restrict__ flag) {
  int i = blockIdx.x * 256 + threadIdx.x;
  if (i >= n8) return;
  uint4 outv;
  if (*flag) {
    const float4* s = (const float4*)src + (size_t)i * 2;
    float4 a = s[0], b = s[1];
    outv.x = pack2bf(a.x, a.y);
    outv.y = pack2bf(a.z, a.w);
    outv.z = pack2bf(b.x, b.y);
    outv.w = pack2bf(b.z, b.w);
  } else {
    outv = ((const uint4*)src)[i];
  }
  ((uint4*)dst)[i] = outv;
}

// ---- b_qkv convert with Q-column pre-scale (cols with (i%192)<64)
__global__ void convert_bias_qkv(const void* __restrict__ src, bf16* __restrict__ dst,
                                 const int* __restrict__ flag) {
  int i = blockIdx.x * 256 + threadIdx.x;
  if (i >= 3072) return;
  float v = (*flag) ? ((const float*)src)[i]
                    : __bfloat162float(((const bf16*)src)[i]);
  if ((i % 192) < 64) v *= CEXP;
  dst[i] = __float2bfloat16(v);
}

// ---- transpose src[R][C] -> dst[C][R] (bf16 out); qscale: scale rows n with
// (n%192)<64 by CEXP (W_qkv Q columns -> exp2 domain).
__global__ __launch_bounds__(256) void transpose_bf16(
    const void* __restrict__ src, bf16* __restrict__ dst, int R, int Cc,
    const int* __restrict__ flag, int qscale) {
  __shared__ float tile[32][33];
  const int c0 = blockIdx.x * 32, r0 = blockIdx.y * 32;
  const int tx = threadIdx.x & 31, ty = threadIdx.x >> 5;  // 32 x 8
  const bool f32 = (*flag != 0);
#pragma unroll
  for (int it = 0; it < 4; ++it) {
    int r = ty + it * 8;
    float v;
    if (f32) v = ((const float*)src)[(size_t)(r0 + r) * Cc + c0 + tx];
    else     v = __bfloat162float(((const bf16*)src)[(size_t)(r0 + r) * Cc + c0 + tx]);
    tile[r][tx] = v;
  }
  __syncthreads();
#pragma unroll
  for (int it = 0; it < 4; ++it) {
    int r = ty + it * 8;   // dst row n = c0 + r
    float vv = tile[tx][r];
    if (qscale && (((c0 + r) % 192) < 64)) vv *= CEXP;
    dst[(size_t)(c0 + r) * R + r0 + tx] = __float2bfloat16(vv);
  }
}

// ---- V pre-transpose: Vtg[bh][d][key] (d<64, key<2048) from permuted qkv.
__global__ __launch_bounds__(256) void transpose_v(const bf16* __restrict__ qkv,
                                                   bf16* __restrict__ vtg)
{
  __shared__ short tile[64][72];
  const int bh = blockIdx.x;
  const int k0 = blockIdx.y * 64;
  const unsigned short* qk = (const unsigned short*)qkv + (size_t)bh * 393216;
  const int key = threadIdx.x & 63;
  const int dv = threadIdx.x >> 6;      // 0..3 -> d-range dv*16
  const int gk = k0 + key;
  const unsigned short* src =
      qk + (size_t)(gk >> 4) * 3072 + (gk & 15) * 192 + 128 + dv * 16;
  *(short8*)&tile[key][dv * 16] = *(const short8*)src;
  *(short8*)&tile[key][dv * 16 + 8] = *(const short8*)(src + 8);
  __syncthreads();
  const int d = threadIdx.x & 63;
  const int kv = threadIdx.x >> 6;      // 0..3 -> key-range kv*16
  unsigned short* dst =
      (unsigned short*)vtg + ((size_t)bh * 64 + d) * 2048 + k0 + kv * 16;
  short8 a, b;
#pragma unroll
  for (int j = 0; j < 8; ++j) {
    a[j] = tile[kv * 16 + j][d];
    b[j] = tile[kv * 16 + 8 + j][d];
  }
  *(short8*)dst = a;
  *(short8*)(dst + 8) = b;
}

// ---------------- MFMA GEMM (m97 pattern): C[M,N] = A[M,K] @ BT[N,K]^T + bias
__global__ __launch_bounds__(256) void gemm_mfma(
    const bf16* __restrict__ A, const bf16* __restrict__ BT,
    const bf16* __restrict__ bias, void* __restrict__ C,
    int M, int N, int K, int store_mode, const int* __restrict__ flag)
{
  __shared__ alignas(16) unsigned short As[128 * 32];  // [m][k] contiguous
  __shared__ alignas(16) unsigned short Bs[128 * 32];  // [n][k] contiguous
  const bool store_f32 = store_mode && (*flag != 0);
  const int tid = threadIdx.x;
  const int wave = tid >> 6, lane = tid & 63;
  const int l15 = lane & 15, l4 = lane >> 4;
  const int m0 = blockIdx.y * 128, n0 = blockIdx.x * 128;
  const int wm = (wave & 1) * 64, wn = (wave >> 1) * 64;

  const int srow = wave * 32 + (lane >> 2);
  const int skv = (lane & 3) * 8;
  const bf16* ga = A + (size_t)(m0 + srow) * K + skv;
  const bf16* gb = BT + (size_t)(n0 + srow) * K + skv;
  unsigned short* la = As + (wave * 32) * 32;
  unsigned short* lb = Bs + (wave * 32) * 32;

  f32x4 acc[4][4] = {};

  for (int k0 = 0; k0 < K; k0 += 32) {
    __syncthreads();
    gload_lds16(ga, la);
    gload_lds16(ga + (size_t)16 * K, la + 16 * 32);
    gload_lds16(gb, lb);
    gload_lds16(gb + (size_t)16 * K, lb + 16 * 32);
    ga += 32; gb += 32;
    __syncthreads();

    short8 af[4], bfr[4];
#pragma unroll
    for (int i = 0; i < 4; ++i) {
      af[i]  = *(const short8*)(As + (wm + i * 16 + l15) * 32 + l4 * 8);
      bfr[i] = *(const short8*)(Bs + (wn + i * 16 + l15) * 32 + l4 * 8);
    }
#pragma unroll
    for (int i = 0; i < 4; ++i)
#pragma unroll
      for (int j = 0; j < 4; ++j)
        acc[i][j] = __builtin_amdgcn_mfma_f32_16x16x32_bf16(af[i], bfr[j], acc[i][j], 0, 0, 0);
  }

#pragma unroll
  for (int j = 0; j < 4; ++j) {
    const int n = n0 + wn + j * 16 + l15;
    const float bv = __bfloat162float(bias[n]);
#pragma unroll
    for (int i = 0; i < 4; ++i) {
#pragma unroll
      for (int r = 0; r < 4; ++r) {
        const int mrow = m0 + wm + i * 16 + l4 * 4 + r;
        const float v = acc[i][j][r] + bv;
        if (store_f32) ((float*)C)[(size_t)mrow * N + n] = v;
        else           ((bf16*)C)[(size_t)mrow * N + n] = __float2bfloat16(v);
      }
    }
  }
}

// ---------------- MFMA flash attention: 4 waves x QBLK=32, shared LDS K/V.
// grid (64 bh, 16 y); block owns chunk qc = 15-y (longest first; 2qc+2 iters).
// K/V double-buffered frag-shaped LDS (1 gload_lds16/thread/tensor/iter);
// S^T = mfma(K,Q) per q-subtile h; lane-local softmax with T13 defer-max;
// P roundtrip via HALVED per-wave LDS (16 rows, h processed sequentially);
// O^T = mfma(Vt,P). One barrier/iter. LDS 41984B -> 3 blocks/CU.
__global__ __launch_bounds__(256) void attn_mfma(const bf16* __restrict__ qkv,
                                                 const bf16* __restrict__ vtg,
                                                 bf16* __restrict__ sa)
{
  __shared__ alignas(16) short Ks[2][4096];   // [buf] [dchunk8][key64][8]
  __shared__ alignas(16) short Vs[2][4096];   // [buf] [kchunk8][d64][8]
  __shared__ alignas(16) short Ps[4][1152];   // per-wave [q16][key64 pad->72]
  const int tid = threadIdx.x;
  const int bh = blockIdx.x;
  const int qc = 15 - blockIdx.y;             // longest chunks first
  const size_t base = (size_t)bh * 393216;    // (bh*128)*3072
  const int w = tid >> 6, lane = tid & 63;
  const int l15 = lane & 15, l4 = lane >> 4;
  const unsigned short* qk = (const unsigned short*)qkv;
  const unsigned short* vtb = (const unsigned short*)vtg + (size_t)bh * 131072;  // 64*2048
  short* psw = &Ps[w][0];

  // staging sources (lane part); kt adds 12288 (K: 4 rows) / 64 (V: keys)
  const unsigned short* ksrc0 = qk + base + (size_t)(lane >> 4) * 3072 + (lane & 15) * 192 + 64;
  const unsigned short* vsrc0 = vtb + (size_t)lane * 2048;

  const int ktmax = 2 * qc + 1;

  // Q frags: B[n=q(16h+l15)][k=d(32kk+8l4+j)]; sa row u = qc*8+2w+h, r=l15
  short8 qf[2][2];
#pragma unroll
  for (int h = 0; h < 2; ++h) {
    const unsigned short* pq =
        qk + base + (size_t)(qc * 8 + 2 * w + h) * 3072 + l15 * 192 + l4 * 8;
    qf[h][0] = *(const short8*)pq;
    qf[h][1] = *(const short8*)(pq + 32);
  }

  f32x4 o[2][4] = {};                 // O^T: col=q(l15), row=d(16jn+4l4+r)
  float ml[2] = {-__builtin_inff(), -__builtin_inff()};
  float ls[2] = {0.f, 0.f};
  int cur = 0;

  // prologue: stage kt=0 into buf 0
#pragma unroll
  for (int rd = 0; rd < 2; ++rd) {
    const int dc = w + 4 * rd;
    gload_lds16(ksrc0 + dc * 8, &Ks[0][dc * 512]);
    gload_lds16(vsrc0 + dc * 8, &Vs[0][dc * 512]);
  }
  __syncthreads();

  for (int kt = 0; kt <= ktmax; ++kt) {
    // stage kt+1 into the other buffer (flies under this iter's compute)
    if (kt < ktmax) {
      const int nb = cur ^ 1;
#pragma unroll
      for (int rd = 0; rd < 2; ++rd) {
        const int dc = w + 4 * rd;
        gload_lds16(ksrc0 + (size_t)(kt + 1) * 12288 + dc * 8, &Ks[nb][dc * 512]);
        gload_lds16(vsrc0 + (kt + 1) * 64 + dc * 8, &Vs[nb][dc * 512]);
      }
    }

    // ---- S^T = K . Q^T per q-subtile h: col=q(l15), row=key(16t+4l4+r)
    f32x4 sc[2][4];
#pragma unroll
    for (int t = 0; t < 4; ++t) {
      const short8 kf0 = *(const short8*)&Ks[cur][(l4) * 512 + (16 * t + l15) * 8];
      const short8 kf1 = *(const short8*)&Ks[cur][(4 + l4) * 512 + (16 * t + l15) * 8];
#pragma unroll
      for (int h = 0; h < 2; ++h) {
        f32x4 c = {};
        c = __builtin_amdgcn_mfma_f32_16x16x32_bf16(kf0, qf[h][0], c, 0, 0, 0);
        c = __builtin_amdgcn_mfma_f32_16x16x32_bf16(kf1, qf[h][1], c, 0, 0, 0);
        sc[h][t] = c;
      }
    }

    // ---- causal mask on the (at most 2) diagonal iterations
    if (kt >= 2 * qc) {
      const int kb = 64 * (kt - 2 * qc);
#pragma unroll
      for (int h = 0; h < 2; ++h) {
        const int thr = 32 * w + 16 * h + l15;
#pragma unroll
        for (int t = 0; t < 4; ++t)
#pragma unroll
          for (int r = 0; r < 4; ++r)
            if (kb + 16 * t + 4 * l4 + r > thr) sc[h][t][r] = -__builtin_inff();
      }
    }

    // ---- lane-local online softmax per h + T13 defer-max (THR=8):
    // skip alpha/rescale when no lane's tile-max exceeds running max by >8.
    unsigned int pk2[2][4][2];
#pragma unroll
    for (int h = 0; h < 2; ++h) {
      float mx = -__builtin_inff();
#pragma unroll
      for (int t = 0; t < 4; ++t)
#pragma unroll
        for (int r = 0; r < 4; ++r) mx = fmaxf(mx, sc[h][t][r]);
      mx = fmaxf(mx, __shfl_xor(mx, 16, 64));
      mx = fmaxf(mx, __shfl_xor(mx, 32, 64));
      if (!__all(mx <= ml[h] + 8.f)) {   // wave-uniform rescale branch
        const float m_new = fmaxf(ml[h], mx);
        const float alpha = __builtin_amdgcn_exp2f(ml[h] - m_new);
        ml[h] = m_new;
        ls[h] *= alpha;
#pragma unroll
        for (int jn = 0; jn < 4; ++jn)
#pragma unroll
          for (int r = 0; r < 4; ++r) o[h][jn][r] *= alpha;
      }
      const float m_new = ml[h];
      float s = 0.f;
#pragma unroll
      for (int t = 0; t < 4; ++t) {
        float p0 = __builtin_amdgcn_exp2f(sc[h][t][0] - m_new);
        float p1 = __builtin_amdgcn_exp2f(sc[h][t][1] - m_new);
        float p2 = __builtin_amdgcn_exp2f(sc[h][t][2] - m_new);
        float p3 = __builtin_amdgcn_exp2f(sc[h][t][3] - m_new);
        s += (p0 + p1) + (p2 + p3);
        pk2[h][t][0] = pack2bf(p0, p1);
        pk2[h][t][1] = pack2bf(p2, p3);
      }
      s += __shfl_xor(s, 16, 64);
      s += __shfl_xor(s, 32, 64);
      ls[h] += s;
    }

    // ---- P roundtrip through HALVED per-wave LDS: h sequential (same-wave
    // program order; compiler inserts lgkmcnt between write/read/overwrite)
    short8 pf[2][2];
#pragma unroll
    for (int h = 0; h < 2; ++h) {
#pragma unroll
      for (int t = 0; t < 4; ++t) {
        uint2 wv; wv.x = pk2[h][t][0]; wv.y = pk2[h][t][1];
        *(uint2*)(psw + l15 * 72 + 16 * t + 4 * l4) = wv;
      }
      pf[h][0] = *(const short8*)(psw + l15 * 72 + 8 * l4);
      pf[h][1] = *(const short8*)(psw + l15 * 72 + 32 + 8 * l4);
    }

    // ---- O^T += V^T . P^T : A[m=d(16jn+l15)][k=key(32ks+8l4+j)] from Vs
#pragma unroll
    for (int jn = 0; jn < 4; ++jn)
#pragma unroll
      for (int ks = 0; ks < 2; ++ks) {
        const short8 vf =
            *(const short8*)&Vs[cur][(4 * ks + l4) * 512 + (16 * jn + l15) * 8];
#pragma unroll
        for (int h = 0; h < 2; ++h)
          o[h][jn] = __builtin_amdgcn_mfma_f32_16x16x32_bf16(vf, pf[h][ks], o[h][jn], 0, 0, 0);
      }

    __syncthreads();   // staged kt+1 ready (vmcnt drain); buf reads done
    cur ^= 1;
  }

  // ---- epilogue: q row u = qc*8+2w+h, r=l15; col = 64*l15 + 16jn+4l4+r
#pragma unroll
  for (int h = 0; h < 2; ++h) {
    const float inv = 1.0f / ls[h];
    unsigned short* so =
        (unsigned short*)sa + (size_t)(bh * 128 + qc * 8 + 2 * w + h) * 1024;
#pragma unroll
    for (int jn = 0; jn < 4; ++jn) {
      uint2 wv;
      wv.x = pack2bf(o[h][jn][0] * inv, o[h][jn][1] * inv);
      wv.y = pack2bf(o[h][jn][2] * inv, o[h][jn][3] * inv);
      *(uint2*)(so + l15 * 64 + jn * 16 + l4 * 4) = wv;
    }
  }
}

extern "C" void kernel_launch(void* const* d_in, const int* in_sizes, int n_in,
                              void* d_out, int out_size, void* d_ws, size_t ws_size,
                              hipStream_t stream)
{
  const void* x_raw    = d_in[0];  // [4,2048,1024]
  const void* Wqkv_raw = d_in[1];  // [1024,3072]
  const void* bqkv_raw = d_in[2];  // [3072]
  const void* Wout_raw = d_in[3];  // [1024,1024]
  const void* bout_raw = d_in[4];  // [1024]

  char* ws = (char*)d_ws;
  int*  flag   = (int*)ws;                                  //   256 B
  bf16* xb     = (bf16*)(ws + 256);                         //  16 MiB (8192*1024)
  bf16* wqkvT  = xb + (size_t)8192 * 1024;                  //   6 MiB (3072*1024, [N][K])
  bf16* bqkvb  = wqkvT + (size_t)3072 * 1024;               //   6 KiB
  bf16* woutT  = bqkvb + 4096;                              //   2 MiB (1024*1024, [N][K])
  bf16* boutb  = woutT + (size_t)1024 * 1024;               //   2 KiB
  bf16* qkv    = boutb + 4096;                              //  48 MiB (8192*3072)
  bf16* sa     = qkv + (size_t)8192 * 3072;                 //  16 MiB (8192*1024)
  bf16* vtg    = sa + (size_t)8192 * 1024;                  //  16 MiB (64*64*2048)

  detect_kernel<<<1, 64, 0, stream>>>((const unsigned int*)x_raw, flag);

  convert_kernel<<<(8192 * 1024 / 8 + 255) / 256, 256, 0, stream>>>(x_raw, xb, 8192 * 1024 / 8, flag);
  convert_bias_qkv<<<12, 256, 0, stream>>>(bqkv_raw, bqkvb, flag);
  convert_kernel<<<1, 256, 0, stream>>>(bout_raw, boutb, 1024 / 8, flag);
  transpose_bf16<<<dim3(3072 / 32, 1024 / 32), 256, 0, stream>>>(Wqkv_raw, wqkvT, 1024, 3072, flag, 1);
  transpose_bf16<<<dim3(1024 / 32, 1024 / 32), 256, 0, stream>>>(Wout_raw, woutT, 1024, 1024, flag, 0);

  // 1) qkv = x @ W_qkv + b_qkv   (M=8192, N=3072, K=1024); Q cols pre-scaled
  gemm_mfma<<<dim3(3072 / 128, 8192 / 128), 256, 0, stream>>>(
      xb, wqkvT, bqkvb, qkv, 8192, 3072, 1024, 0, flag);
  // 1b) V pre-transpose: Vtg[bh][d][key]
  transpose_v<<<dim3(64, 32), 256, 0, stream>>>(qkv, vtg);
  // 2) MFMA flash attention: one chunk per block, LDS 41984B -> 3 blocks/CU
  attn_mfma<<<dim3(64, 16), 256, 0, stream>>>(qkv, vtg, sa);
  // 3) out = sa @ W_out + b_out  (M=8192, N=1024, K=1024)
  gemm_mfma<<<dim3(1024 / 128, 8192 / 128), 256, 0, stream>>>(
      sa, woutT, boutb, d_out, 8192, 1024, 1024, 1, flag);
}

// Round 10
// 293.998 us; speedup vs baseline: 1.7030x; 1.0276x over previous
//
#include <hip/hip_runtime.h>
#include <hip/hip_bf16.h>

using bf16 = __hip_bfloat16;

typedef __attribute__((ext_vector_type(8))) short short8;   // 8 x bf16 (4 VGPRs)
typedef __attribute__((ext_vector_type(4))) float f32x4;    // MFMA C/D

// MaskedMSA: B=4, S=2048, E=1024, HIDDEN=1024, HEADS=16
// Reference reshape mixes seq/hidden: with t=16u+r (u<128, r<16):
//   q[b,h,t,e] = qkv[b, 128h+u, 192r +   0 + e]
//   k[b,h,t,e] = qkv[b, 128h+u, 192r +  64 + e]
//   v[b,h,t,e] = qkv[b, 128h+u, 192r + 128 + e]
// Output: sa[b,h,t,e] -> out row 128h+u, col 64r+e. Causal mask on permuted t.
// Q columns of W_qkv/b_qkv are pre-scaled by scale*log2(e): exp2-domain scores.
//
// R1-R4: 1-wave 16x16 q-tile = structural plateau (~165us floor).
// R5 (WIN 165->96): QBLK=32/wave, coop frag-shaped LDS K/V, dbuf, 1 barrier/iter.
// R8/R9: occupancy pinned at ~20% (2 wg/CU) under grid 4/CU, LDS 51K->42K,
// VGPR 92 -> the cap is workgroups/CU, not a shrinkable resource.
// R10: 8-wave (512-thread) blocks -- wave-group pairing: waves 0-3 = long
// chunk (15-pr), waves 4-7 = short chunk (pr), ONE shared K/V stream
// (K staged by group 0, V by group 1; short group compute-gated wave-uniform).
// 2 wg/CU x 8 waves = 16 waves/CU. Uniform 34 iters/block, grid 64x8.
// Plus T1 bijective XCD swizzle on both GEMMs (A-panel L2 locality).

#define CEXP 0.03188127742677263f  // (2*1024)^-0.5 * log2(e)

__device__ __forceinline__ unsigned short f2bf(float v) {
  bf16 h = __float2bfloat16(v);
  return *(unsigned short*)&h;
}
__device__ __forceinline__ unsigned int pack2bf(float a, float b) {
  return (unsigned int)f2bf(a) | ((unsigned int)f2bf(b) << 16);
}

// async global->LDS, 16B per lane; LDS dest = wave-uniform base + lane*16.
__device__ __forceinline__ void gload_lds16(const void* g, void* lds) {
  __builtin_amdgcn_global_load_lds(
      (const __attribute__((address_space(1))) unsigned int*)(g),
      (__attribute__((address_space(3))) unsigned int*)(lds), 16, 0, 0);
}

// ---- dtype detect: flag=1 if fp32 I/O, flag=0 if bf16 I/O.
__global__ void detect_kernel(const unsigned int* __restrict__ x, int* __restrict__ flag) {
  unsigned int w = x[threadIdx.x];
  unsigned int e = (w >> 7) & 0xFF;
  bool inband = (e >= 96 && e <= 133);
  unsigned long long m = __ballot(inband);
  if (threadIdx.x == 0) flag[0] = (__popcll(m) >= 48) ? 0 : 1;
}

// ---- convert n8*8 elements to bf16 (copy if already bf16)
__global__ __launch_bounds__(256) void convert_kernel(
    const void* __restrict__ src, bf16* __restrict__ dst, int n8,
    const int* __restrict__ flag) {
  int i = blockIdx.x * 256 + threadIdx.x;
  if (i >= n8) return;
  uint4 outv;
  if (*flag) {
    const float4* s = (const float4*)src + (size_t)i * 2;
    float4 a = s[0], b = s[1];
    outv.x = pack2bf(a.x, a.y);
    outv.y = pack2bf(a.z, a.w);
    outv.z = pack2bf(b.x, b.y);
    outv.w = pack2bf(b.z, b.w);
  } else {
    outv = ((const uint4*)src)[i];
  }
  ((uint4*)dst)[i] = outv;
}

// ---- b_qkv convert with Q-column pre-scale (cols with (i%192)<64)
__global__ void convert_bias_qkv(const void* __restrict__ src, bf16* __restrict__ dst,
                                 const int* __restrict__ flag) {
  int i = blockIdx.x * 256 + threadIdx.x;
  if (i >= 3072) return;
  float v = (*flag) ? ((const float*)src)[i]
                    : __bfloat162float(((const bf16*)src)[i]);
  if ((i % 192) < 64) v *= CEXP;
  dst[i] = __float2bfloat16(v);
}

// ---- transpose src[R][C] -> dst[C][R] (bf16 out); qscale: scale rows n with
// (n%192)<64 by CEXP (W_qkv Q columns -> exp2 domain).
__global__ __launch_bounds__(256) void transpose_bf16(
    const void* __restrict__ src, bf16* __restrict__ dst, int R, int Cc,
    const int* __restrict__ flag, int qscale) {
  __shared__ float tile[32][33];
  const int c0 = blockIdx.x * 32, r0 = blockIdx.y * 32;
  const int tx = threadIdx.x & 31, ty = threadIdx.x >> 5;  // 32 x 8
  const bool f32 = (*flag != 0);
#pragma unroll
  for (int it = 0; it < 4; ++it) {
    int r = ty + it * 8;
    float v;
    if (f32) v = ((const float*)src)[(size_t)(r0 + r) * Cc + c0 + tx];
    else     v = __bfloat162float(((const bf16*)src)[(size_t)(r0 + r) * Cc + c0 + tx]);
    tile[r][tx] = v;
  }
  __syncthreads();
#pragma unroll
  for (int it = 0; it < 4; ++it) {
    int r = ty + it * 8;   // dst row n = c0 + r
    float vv = tile[tx][r];
    if (qscale && (((c0 + r) % 192) < 64)) vv *= CEXP;
    dst[(size_t)(c0 + r) * R + r0 + tx] = __float2bfloat16(vv);
  }
}

// ---- V pre-transpose: Vtg[bh][d][key] (d<64, key<2048) from permuted qkv.
__global__ __launch_bounds__(256) void transpose_v(const bf16* __restrict__ qkv,
                                                   bf16* __restrict__ vtg)
{
  __shared__ short tile[64][72];
  const int bh = blockIdx.x;
  const int k0 = blockIdx.y * 64;
  const unsigned short* qk = (const unsigned short*)qkv + (size_t)bh * 393216;
  const int key = threadIdx.x & 63;
  const int dv = threadIdx.x >> 6;      // 0..3 -> d-range dv*16
  const int gk = k0 + key;
  const unsigned short* src =
      qk + (size_t)(gk >> 4) * 3072 + (gk & 15) * 192 + 128 + dv * 16;
  *(short8*)&tile[key][dv * 16] = *(const short8*)src;
  *(short8*)&tile[key][dv * 16 + 8] = *(const short8*)(src + 8);
  __syncthreads();
  const int d = threadIdx.x & 63;
  const int kv = threadIdx.x >> 6;      // 0..3 -> key-range kv*16
  unsigned short* dst =
      (unsigned short*)vtg + ((size_t)bh * 64 + d) * 2048 + k0 + kv * 16;
  short8 a, b;
#pragma unroll
  for (int j = 0; j < 8; ++j) {
    a[j] = tile[kv * 16 + j][d];
    b[j] = tile[kv * 16 + 8 + j][d];
  }
  *(short8*)dst = a;
  *(short8*)(dst + 8) = b;
}

// ---------------- MFMA GEMM (m97 pattern): C[M,N] = A[M,K] @ BT[N,K]^T + bias
// T1: bijective XCD swizzle of the linear block id (m204) -- consecutive
// y-rows (shared A panels) stay on one XCD's L2.
__global__ __launch_bounds__(256) void gemm_mfma(
    const bf16* __restrict__ A, const bf16* __restrict__ BT,
    const bf16* __restrict__ bias, void* __restrict__ C,
    int M, int N, int K, int store_mode, const int* __restrict__ flag)
{
  __shared__ alignas(16) unsigned short As[128 * 32];  // [m][k] contiguous
  __shared__ alignas(16) unsigned short Bs[128 * 32];  // [n][k] contiguous
  const bool store_f32 = store_mode && (*flag != 0);
  const int tid = threadIdx.x;
  const int wave = tid >> 6, lane = tid & 63;
  const int l15 = lane & 15, l4 = lane >> 4;

  // ---- XCD-bijective block remap (grids here are multiples of 8)
  const int nwg = gridDim.x * gridDim.y;
  const int orig = blockIdx.x + gridDim.x * blockIdx.y;
  const int qn = nwg >> 3, rn = nwg & 7;
  const int xcd = orig & 7, loc = orig >> 3;
  const int swz = (xcd < rn ? xcd * (qn + 1) : rn * (qn + 1) + (xcd - rn) * qn) + loc;
  const int bx = swz % gridDim.x, by = swz / gridDim.x;

  const int m0 = by * 128, n0 = bx * 128;
  const int wm = (wave & 1) * 64, wn = (wave >> 1) * 64;

  const int srow = wave * 32 + (lane >> 2);
  const int skv = (lane & 3) * 8;
  const bf16* ga = A + (size_t)(m0 + srow) * K + skv;
  const bf16* gb = BT + (size_t)(n0 + srow) * K + skv;
  unsigned short* la = As + (wave * 32) * 32;
  unsigned short* lb = Bs + (wave * 32) * 32;

  f32x4 acc[4][4] = {};

  for (int k0 = 0; k0 < K; k0 += 32) {
    __syncthreads();
    gload_lds16(ga, la);
    gload_lds16(ga + (size_t)16 * K, la + 16 * 32);
    gload_lds16(gb, lb);
    gload_lds16(gb + (size_t)16 * K, lb + 16 * 32);
    ga += 32; gb += 32;
    __syncthreads();

    short8 af[4], bfr[4];
#pragma unroll
    for (int i = 0; i < 4; ++i) {
      af[i]  = *(const short8*)(As + (wm + i * 16 + l15) * 32 + l4 * 8);
      bfr[i] = *(const short8*)(Bs + (wn + i * 16 + l15) * 32 + l4 * 8);
    }
#pragma unroll
    for (int i = 0; i < 4; ++i)
#pragma unroll
      for (int j = 0; j < 4; ++j)
        acc[i][j] = __builtin_amdgcn_mfma_f32_16x16x32_bf16(af[i], bfr[j], acc[i][j], 0, 0, 0);
  }

#pragma unroll
  for (int j = 0; j < 4; ++j) {
    const int n = n0 + wn + j * 16 + l15;
    const float bv = __bfloat162float(bias[n]);
#pragma unroll
    for (int i = 0; i < 4; ++i) {
#pragma unroll
      for (int r = 0; r < 4; ++r) {
        const int mrow = m0 + wm + i * 16 + l4 * 4 + r;
        const float v = acc[i][j][r] + bv;
        if (store_f32) ((float*)C)[(size_t)mrow * N + n] = v;
        else           ((bf16*)C)[(size_t)mrow * N + n] = __float2bfloat16(v);
      }
    }
  }
}

// ---------------- MFMA flash attention: 8 waves (512 thr), paired chunks.
// grid (64 bh, 8 pr). Waves 0-3 own chunk A = 15-pr (long), waves 4-7 own
// chunk B = pr (short); uniform 34 iters/block. ONE shared K/V LDS stream:
// group 0 stages K, group 1 stages V (2 gload_lds16/thread/iter), dbuf,
// one barrier/iter. Per wave: QBLK=32 (2 subtiles h), S^T = mfma(K,Q),
// lane-local softmax + T13 defer-max, P roundtrip (per-wave LDS, h
// sequential), O^T = mfma(Vt,P). Short group compute-gated (wave-uniform).
__global__ __launch_bounds__(512) void attn_mfma(const bf16* __restrict__ qkv,
                                                 const bf16* __restrict__ vtg,
                                                 bf16* __restrict__ sa)
{
  __shared__ alignas(16) short Ks[2][4096];   // [buf] [dchunk8][key64][8]
  __shared__ alignas(16) short Vs[2][4096];   // [buf] [kchunk8][d64][8]
  __shared__ alignas(16) short Ps[8][1152];   // per-wave [q16][key64 pad->72]
  const int tid = threadIdx.x;
  const int bh = blockIdx.x;
  const int pr = blockIdx.y;                  // 0..7
  const size_t base = (size_t)bh * 393216;    // (bh*128)*3072
  const int w = tid >> 6;                     // 0..7
  const int g = w >> 2;                       // 0 = chunk A (long), 1 = chunk B
  const int wl = w & 3;
  const int lane = tid & 63;
  const int l15 = lane & 15, l4 = lane >> 4;
  const unsigned short* qk = (const unsigned short*)qkv;
  const unsigned short* vtb = (const unsigned short*)vtg + (size_t)bh * 131072;  // 64*2048
  short* psw = &Ps[w][0];

  const int qc = g ? pr : (15 - pr);          // this wave-group's chunk
  const int my_ktmax  = 2 * qc + 1;
  const int blk_ktmax = 2 * (15 - pr) + 1;    // union range (= A's)

  // staging source (wave-group picks its tensor): group 0 -> K, group 1 -> V.
  // per kt step: K advances 12288 (4 rows), V advances 64 (keys).
  const unsigned short* gsrc0 =
      g ? (vtb + (size_t)lane * 2048)
        : (qk + base + (size_t)(lane >> 4) * 3072 + (lane & 15) * 192 + 64);
  const size_t gstep = g ? 64 : 12288;

  // Q frags: B[n=q(16h+l15)][k=d(32kk+8l4+j)]; sa row u = qc*8+2wl+h, r=l15
  short8 qf[2][2];
#pragma unroll
  for (int h = 0; h < 2; ++h) {
    const unsigned short* pq =
        qk + base + (size_t)(qc * 8 + 2 * wl + h) * 3072 + l15 * 192 + l4 * 8;
    qf[h][0] = *(const short8*)pq;
    qf[h][1] = *(const short8*)(pq + 32);
  }

  f32x4 o[2][4] = {};                 // O^T: col=q(l15), row=d(16jn+4l4+r)
  float ml[2] = {-__builtin_inff(), -__builtin_inff()};
  float ls[2] = {0.f, 0.f};
  int cur = 0;

  // prologue: stage kt=0 into buf 0 (each thread: 2 gloads of its tensor)
  {
    short* dstbuf = g ? &Vs[0][0] : &Ks[0][0];
    gload_lds16(gsrc0 + wl * 8, dstbuf + wl * 512);
    gload_lds16(gsrc0 + (wl + 4) * 8, dstbuf + (wl + 4) * 512);
  }
  __syncthreads();

  for (int kt = 0; kt <= blk_ktmax; ++kt) {
    // stage kt+1 into the other buffer (flies under this iter's compute)
    if (kt < blk_ktmax) {
      short* dstbuf = g ? &Vs[cur ^ 1][0] : &Ks[cur ^ 1][0];
      const unsigned short* s = gsrc0 + (size_t)(kt + 1) * gstep;
      gload_lds16(s + wl * 8, dstbuf + wl * 512);
      gload_lds16(s + (wl + 4) * 8, dstbuf + (wl + 4) * 512);
    }

    if (kt <= my_ktmax) {   // wave-uniform gate (short group idles at tail)
      // ---- S^T = K . Q^T per q-subtile h: col=q(l15), row=key(16t+4l4+r)
      f32x4 sc[2][4];
#pragma unroll
      for (int t = 0; t < 4; ++t) {
        const short8 kf0 = *(const short8*)&Ks[cur][(l4) * 512 + (16 * t + l15) * 8];
        const short8 kf1 = *(const short8*)&Ks[cur][(4 + l4) * 512 + (16 * t + l15) * 8];
#pragma unroll
        for (int h = 0; h < 2; ++h) {
          f32x4 c = {};
          c = __builtin_amdgcn_mfma_f32_16x16x32_bf16(kf0, qf[h][0], c, 0, 0, 0);
          c = __builtin_amdgcn_mfma_f32_16x16x32_bf16(kf1, qf[h][1], c, 0, 0, 0);
          sc[h][t] = c;
        }
      }

      // ---- causal mask on the (at most 2) diagonal iterations
      if (kt >= 2 * qc) {
        const int kb = 64 * (kt - 2 * qc);
#pragma unroll
        for (int h = 0; h < 2; ++h) {
          const int thr = 32 * wl + 16 * h + l15;
#pragma unroll
          for (int t = 0; t < 4; ++t)
#pragma unroll
            for (int r = 0; r < 4; ++r)
              if (kb + 16 * t + 4 * l4 + r > thr) sc[h][t][r] = -__builtin_inff();
        }
      }

      // ---- lane-local online softmax per h + T13 defer-max (THR=8)
      unsigned int pk2[2][4][2];
#pragma unroll
      for (int h = 0; h < 2; ++h) {
        float mx = -__builtin_inff();
#pragma unroll
        for (int t = 0; t < 4; ++t)
#pragma unroll
          for (int r = 0; r < 4; ++r) mx = fmaxf(mx, sc[h][t][r]);
        mx = fmaxf(mx, __shfl_xor(mx, 16, 64));
        mx = fmaxf(mx, __shfl_xor(mx, 32, 64));
        if (!__all(mx <= ml[h] + 8.f)) {   // wave-uniform rescale branch
          const float m_new = fmaxf(ml[h], mx);
          const float alpha = __builtin_amdgcn_exp2f(ml[h] - m_new);
          ml[h] = m_new;
          ls[h] *= alpha;
#pragma unroll
          for (int jn = 0; jn < 4; ++jn)
#pragma unroll
            for (int r = 0; r < 4; ++r) o[h][jn][r] *= alpha;
        }
        const float m_new = ml[h];
        float s = 0.f;
#pragma unroll
        for (int t = 0; t < 4; ++t) {
          float p0 = __builtin_amdgcn_exp2f(sc[h][t][0] - m_new);
          float p1 = __builtin_amdgcn_exp2f(sc[h][t][1] - m_new);
          float p2 = __builtin_amdgcn_exp2f(sc[h][t][2] - m_new);
          float p3 = __builtin_amdgcn_exp2f(sc[h][t][3] - m_new);
          s += (p0 + p1) + (p2 + p3);
          pk2[h][t][0] = pack2bf(p0, p1);
          pk2[h][t][1] = pack2bf(p2, p3);
        }
        s += __shfl_xor(s, 16, 64);
        s += __shfl_xor(s, 32, 64);
        ls[h] += s;
      }

      // ---- P roundtrip through per-wave LDS: h sequential (program order)
      short8 pf[2][2];
#pragma unroll
      for (int h = 0; h < 2; ++h) {
#pragma unroll
        for (int t = 0; t < 4; ++t) {
          uint2 wv; wv.x = pk2[h][t][0]; wv.y = pk2[h][t][1];
          *(uint2*)(psw + l15 * 72 + 16 * t + 4 * l4) = wv;
        }
        pf[h][0] = *(const short8*)(psw + l15 * 72 + 8 * l4);
        pf[h][1] = *(const short8*)(psw + l15 * 72 + 32 + 8 * l4);
      }

      // ---- O^T += V^T . P^T : A[m=d(16jn+l15)][k=key(32ks+8l4+j)] from Vs
#pragma unroll
      for (int jn = 0; jn < 4; ++jn)
#pragma unroll
        for (int ks = 0; ks < 2; ++ks) {
          const short8 vf =
              *(const short8*)&Vs[cur][(4 * ks + l4) * 512 + (16 * jn + l15) * 8];
#pragma unroll
          for (int h = 0; h < 2; ++h)
            o[h][jn] = __builtin_amdgcn_mfma_f32_16x16x32_bf16(vf, pf[h][ks], o[h][jn], 0, 0, 0);
        }
    }

    __syncthreads();   // staged kt+1 ready (vmcnt drain); buf reads done
    cur ^= 1;
  }

  // ---- epilogue: q row u = qc*8+2wl+h, r=l15; col = 64*l15 + 16jn+4l4+r
#pragma unroll
  for (int h = 0; h < 2; ++h) {
    const float inv = 1.0f / ls[h];
    unsigned short* so =
        (unsigned short*)sa + (size_t)(bh * 128 + qc * 8 + 2 * wl + h) * 1024;
#pragma unroll
    for (int jn = 0; jn < 4; ++jn) {
      uint2 wv;
      wv.x = pack2bf(o[h][jn][0] * inv, o[h][jn][1] * inv);
      wv.y = pack2bf(o[h][jn][2] * inv, o[h][jn][3] * inv);
      *(uint2*)(so + l15 * 64 + jn * 16 + l4 * 4) = wv;
    }
  }
}

extern "C" void kernel_launch(void* const* d_in, const int* in_sizes, int n_in,
                              void* d_out, int out_size, void* d_ws, size_t ws_size,
                              hipStream_t stream)
{
  const void* x_raw    = d_in[0];  // [4,2048,1024]
  const void* Wqkv_raw = d_in[1];  // [1024,3072]
  const void* bqkv_raw = d_in[2];  // [3072]
  const void* Wout_raw = d_in[3];  // [1024,1024]
  const void* bout_raw = d_in[4];  // [1024]

  char* ws = (char*)d_ws;
  int*  flag   = (int*)ws;                                  //   256 B
  bf16* xb     = (bf16*)(ws + 256);                         //  16 MiB (8192*1024)
  bf16* wqkvT  = xb + (size_t)8192 * 1024;                  //   6 MiB (3072*1024, [N][K])
  bf16* bqkvb  = wqkvT + (size_t)3072 * 1024;               //   6 KiB
  bf16* woutT  = bqkvb + 4096;                              //   2 MiB (1024*1024, [N][K])
  bf16* boutb  = woutT + (size_t)1024 * 1024;               //   2 KiB
  bf16* qkv    = boutb + 4096;                              //  48 MiB (8192*3072)
  bf16* sa     = qkv + (size_t)8192 * 3072;                 //  16 MiB (8192*1024)
  bf16* vtg    = sa + (size_t)8192 * 1024;                  //  16 MiB (64*64*2048)

  detect_kernel<<<1, 64, 0, stream>>>((const unsigned int*)x_raw, flag);

  convert_kernel<<<(8192 * 1024 / 8 + 255) / 256, 256, 0, stream>>>(x_raw, xb, 8192 * 1024 / 8, flag);
  convert_bias_qkv<<<12, 256, 0, stream>>>(bqkv_raw, bqkvb, flag);
  convert_kernel<<<1, 256, 0, stream>>>(bout_raw, boutb, 1024 / 8, flag);
  transpose_bf16<<<dim3(3072 / 32, 1024 / 32), 256, 0, stream>>>(Wqkv_raw, wqkvT, 1024, 3072, flag, 1);
  transpose_bf16<<<dim3(1024 / 32, 1024 / 32), 256, 0, stream>>>(Wout_raw, woutT, 1024, 1024, flag, 0);

  // 1) qkv = x @ W_qkv + b_qkv   (M=8192, N=3072, K=1024); Q cols pre-scaled
  gemm_mfma<<<dim3(3072 / 128, 8192 / 128), 256, 0, stream>>>(
      xb, wqkvT, bqkvb, qkv, 8192, 3072, 1024, 0, flag);
  // 1b) V pre-transpose: Vtg[bh][d][key]
  transpose_v<<<dim3(64, 32), 256, 0, stream>>>(qkv, vtg);
  // 2) MFMA flash attention: 8-wave paired-chunk blocks (grid 64x8, 512 thr)
  attn_mfma<<<dim3(64, 8), 512, 0, stream>>>(qkv, vtg, sa);
  // 3) out = sa @ W_out + b_out  (M=8192, N=1024, K=1024)
  gemm_mfma<<<dim3(1024 / 128, 8192 / 128), 256, 0, stream>>>(
      sa, woutT, boutb, d_out, 8192, 1024, 1024, 1, flag);
}